// Round 2
// baseline (1162.080 us; speedup 1.0000x reference)
//
#include <hip/hip_runtime.h>
#include <math.h>

// B=2 T=2048 D=1024 H=16 DH=64 E=16 K=2 F=2048 CAP=640 DP=256 NPRIM=512
typedef short bf16x8 __attribute__((ext_vector_type(8)));
typedef float f32x4 __attribute__((ext_vector_type(4)));

__device__ __forceinline__ unsigned short f2bf(float f) {
  union { float f; unsigned u; } v; v.f = f;
  return (unsigned short)((v.u + 0x7fff + ((v.u >> 16) & 1)) >> 16);
}
__device__ __forceinline__ float bf2f(unsigned short h) {
  union { unsigned u; float f; } v; v.u = ((unsigned)h) << 16;
  return v.f;
}

// Direct global->LDS DMA, 16B per lane. LDS dest is wave-uniform base + lane*16.
__device__ __forceinline__ void gld16(const unsigned short* g, unsigned short* l) {
  __builtin_amdgcn_global_load_lds((const __attribute__((address_space(1))) void*)g,
                                   (__attribute__((address_space(3))) void*)l, 16, 0, 0);
}

// ---------------- RMSNorm: optional fp32 out, bf16-hi out, optional bf16-lo out ----------------
template <int WF32, int WLO>
__global__ __launch_bounds__(256) void rmsnorm_k(const float* __restrict__ x,
                                                 const float* __restrict__ w,
                                                 float* __restrict__ y,
                                                 unsigned short* __restrict__ yb,
                                                 unsigned short* __restrict__ yl) {
  const long n = blockIdx.x;
  const int t = threadIdx.x;
  const float4 v = ((const float4*)(x + n * 1024))[t];
  float ss = v.x * v.x + v.y * v.y + v.z * v.z + v.w * v.w;
#pragma unroll
  for (int o = 32; o > 0; o >>= 1) ss += __shfl_down(ss, o);
  __shared__ float red[4];
  __shared__ float sc;
  if ((t & 63) == 0) red[t >> 6] = ss;
  __syncthreads();
  if (t == 0) sc = rsqrtf((red[0] + red[1] + red[2] + red[3]) * (1.0f / 1024.0f) + 1e-6f);
  __syncthreads();
  const float s = sc;
  const float4 wv = ((const float4*)w)[t];
  float4 o;
  o.x = v.x * s * wv.x; o.y = v.y * s * wv.y; o.z = v.z * s * wv.z; o.w = v.w * s * wv.w;
  if (WF32) ((float4*)(y + n * 1024))[t] = o;
  ushort4 u = make_ushort4(f2bf(o.x), f2bf(o.y), f2bf(o.z), f2bf(o.w));
  *(ushort4*)(yb + n * 1024 + t * 4) = u;
  if (WLO) {
    ushort4 l = make_ushort4(f2bf(o.x - bf2f(u.x)), f2bf(o.y - bf2f(u.y)),
                             f2bf(o.z - bf2f(u.z)), f2bf(o.w - bf2f(u.w)));
    *(ushort4*)(yl + n * 1024 + t * 4) = l;
  }
}

// ---------------- fused weight hi/lo splits: qkvw (786432 f4) + aow (262144 f4) ----------------
__global__ __launch_bounds__(256) void split2_k(const float* __restrict__ s0,
                                                unsigned short* __restrict__ h0,
                                                unsigned short* __restrict__ l0,
                                                const float* __restrict__ s1,
                                                unsigned short* __restrict__ h1,
                                                unsigned short* __restrict__ l1) {
  const int i = blockIdx.x * 256 + threadIdx.x;  // 4096*256 = 1048576 float4 groups
  const float* s; unsigned short* hp; unsigned short* lp; int off;
  if (i < 786432) { s = s0; hp = h0; lp = l0; off = i; }
  else            { s = s1; hp = h1; lp = l1; off = i - 786432; }
  const float4 v = ((const float4*)s)[off];
  ushort4 h = make_ushort4(f2bf(v.x), f2bf(v.y), f2bf(v.z), f2bf(v.w));
  ushort4 l = make_ushort4(f2bf(v.x - bf2f(h.x)), f2bf(v.y - bf2f(h.y)),
                           f2bf(v.z - bf2f(h.z)), f2bf(v.w - bf2f(h.w)));
  ((ushort4*)hp)[off] = h;
  ((ushort4*)lp)[off] = l;
}

// ---------------- fused phase-C weight conversions (5 regions, 1 launch) ----------------
__global__ __launch_bounds__(256) void cvt5_k(const float* __restrict__ s0, unsigned short* __restrict__ d0,
                                              const float* __restrict__ s1, unsigned short* __restrict__ d1,
                                              const float* __restrict__ s2, unsigned short* __restrict__ d2,
                                              const float* __restrict__ s3, unsigned short* __restrict__ d3,
                                              const float* __restrict__ s4, unsigned short* __restrict__ d4) {
  const int i = blockIdx.x * 256 + threadIdx.x;  // 768*256 = 196608 float4 groups total
  const float* s; unsigned short* d; int off;
  if (i < 65536)       { s = s0; d = d0; off = i; }
  else if (i < 81920)  { s = s1; d = d1; off = i - 65536; }
  else if (i < 98304)  { s = s2; d = d2; off = i - 81920; }
  else if (i < 163840) { s = s3; d = d3; off = i - 98304; }
  else                 { s = s4; d = d4; off = i - 163840; }
  const float4 v = ((const float4*)s)[off];
  ((ushort4*)d)[off] = make_ushort4(f2bf(v.x), f2bf(v.y), f2bf(v.z), f2bf(v.w));
}

// ---------------- transpose-convert: (R,C) fp32 -> (C,R) bf16, batched ----------------
__global__ __launch_bounds__(256) void cvt_t_k(const float* __restrict__ in,
                                               unsigned short* __restrict__ out,
                                               int R, int C) {
  in += (size_t)blockIdx.z * R * C;
  out += (size_t)blockIdx.z * R * C;
  const int r0 = blockIdx.y * 32, c0 = blockIdx.x * 32;
  __shared__ float T[32][33];
  const int tid = threadIdx.x;
  const int li = tid >> 3;
  const int lj = (tid & 7) << 2;
  const float4 v = *(const float4*)(in + (size_t)(r0 + li) * C + c0 + lj);
  T[li][lj + 0] = v.x; T[li][lj + 1] = v.y; T[li][lj + 2] = v.z; T[li][lj + 3] = v.w;
  __syncthreads();
  ushort4 u = make_ushort4(f2bf(T[lj + 0][li]), f2bf(T[lj + 1][li]),
                           f2bf(T[lj + 2][li]), f2bf(T[lj + 3][li]));
  *(ushort4*)(out + (size_t)(c0 + li) * R + r0 + lj) = u;
}

// ---------------- bf16 MFMA GEMM: C(M,N) = alpha * A(M,K) x B(N,K)^T ----------------
// m97 structure: linear LDS + global_load_lds width-16 staging (no reg round-trip).
// MODE: 0=f32 store, 1=f32 +=, 2=bf16 store, 3=bf16 silu store,
//       4=f32 += rowscale[row]*v, 5=f32 atomicAdd to rowmap token (MoE un-scatter)
template <int MODE>
__global__ __launch_bounds__(256) void bgemm(const unsigned short* __restrict__ A,
                                             const unsigned short* __restrict__ B,
                                             void* __restrict__ Cv,
                                             int M, int N, int K,
                                             long sA, long sB, long sC, float alpha,
                                             const float* __restrict__ rowscale,
                                             const int* __restrict__ rowmap,
                                             const float* __restrict__ roww) {
  __shared__ __align__(16) unsigned short As[128 * 32];
  __shared__ __align__(16) unsigned short Bs[128 * 32];
  const int tid = threadIdx.x;
  const int z = blockIdx.z;
  const unsigned short* Ag = A + (size_t)z * sA;
  const unsigned short* Bg = B + (size_t)z * sB;
  const int m0 = blockIdx.y * 128, n0 = blockIdx.x * 128;
  const int lane = tid & 63;
  const int wid = tid >> 6;
  const int wm = (wid >> 1) * 64, wn = (wid & 1) * 64;
  const int fr = lane & 15, fq = lane >> 4;
  const int lr = tid >> 2, lk = (tid & 3) * 8;
  f32x4 acc[4][4] = {};
  const unsigned short* Ap0 = Ag + (size_t)(m0 + lr) * K + lk;
  const unsigned short* Ap1 = Ag + (size_t)(m0 + lr + 64) * K + lk;
  const unsigned short* Bp0 = Bg + (size_t)(n0 + lr) * K + lk;
  const unsigned short* Bp1 = Bg + (size_t)(n0 + lr + 64) * K + lk;
  unsigned short* Asw = As + wid * 512;  // wave-uniform LDS base (bytes: wid*1024)
  unsigned short* Bsw = Bs + wid * 512;
  gld16(Ap0, Asw); gld16(Ap1, Asw + 2048);
  gld16(Bp0, Bsw); gld16(Bp1, Bsw + 2048);
  for (int k0 = 0;;) {
    __syncthreads();  // drains vmcnt: staged tile visible to all waves
    bf16x8 af[4], bv[4];
#pragma unroll
    for (int i = 0; i < 4; ++i) af[i] = *(const bf16x8*)&As[(wm + i * 16 + fr) * 32 + fq * 8];
#pragma unroll
    for (int j = 0; j < 4; ++j) bv[j] = *(const bf16x8*)&Bs[(wn + j * 16 + fr) * 32 + fq * 8];
    __syncthreads();  // all frag reads done -> safe to overwrite tile
    k0 += 32;
    if (k0 < K) {     // next-tile DMA overlaps the MFMAs below
      gld16(Ap0 + k0, Asw); gld16(Ap1 + k0, Asw + 2048);
      gld16(Bp0 + k0, Bsw); gld16(Bp1 + k0, Bsw + 2048);
    }
#pragma unroll
    for (int i = 0; i < 4; ++i)
#pragma unroll
      for (int j = 0; j < 4; ++j)
        acc[i][j] = __builtin_amdgcn_mfma_f32_16x16x32_bf16(af[i], bv[j], acc[i][j], 0, 0, 0);
    if (k0 >= K) break;
  }
#pragma unroll
  for (int i = 0; i < 4; ++i) {
#pragma unroll
    for (int reg = 0; reg < 4; ++reg) {
      const int row = m0 + wm + i * 16 + fq * 4 + reg;
      float rs = 0.f, wgt = 0.f;
      int tok = -1;
      if (MODE == 4) rs = rowscale[row];
      if (MODE == 5) {
        tok = rowmap[z * M + row];
        if (tok >= 0) wgt = roww[z * M + row];
      }
#pragma unroll
      for (int j = 0; j < 4; ++j) {
        const int col = n0 + wn + j * 16 + fr;
        const float v = alpha * acc[i][j][reg];
        if (MODE == 0) {
          ((float*)Cv + (size_t)z * sC)[(size_t)row * N + col] = v;
        } else if (MODE == 1) {
          float* p = (float*)Cv + (size_t)z * sC + (size_t)row * N + col;
          *p += v;
        } else if (MODE == 2) {
          ((unsigned short*)Cv + (size_t)z * sC)[(size_t)row * N + col] = f2bf(v);
        } else if (MODE == 3) {
          const float sv = v / (1.f + expf(-v));
          ((unsigned short*)Cv + (size_t)z * sC)[(size_t)row * N + col] = f2bf(sv);
        } else if (MODE == 4) {
          float* p = (float*)Cv + (size_t)row * N + col;
          *p += rs * v;
        } else if (MODE == 5) {
          if (tok >= 0) atomicAdd((float*)Cv + (size_t)tok * N + col, wgt * v);
        }
      }
    }
  }
}

// ---------------- Fused split-bf16 GEMM: C = (Ah+Al)(Bh+Bl)^T (3-term) ----------------
// MODE: 0 = f32 store, 1 = f32 +=, 2 = f32 store of res[row,col] + v (residual fuse),
//       3 = fused RoPE + hi/lo split QKV output to [bh][t][dh] (no C)
template <int MODE>
__global__ __launch_bounds__(256) void bgemm_s(const unsigned short* __restrict__ Ah,
                                               const unsigned short* __restrict__ Al,
                                               const unsigned short* __restrict__ Bh,
                                               const unsigned short* __restrict__ Bl,
                                               float* __restrict__ C,
                                               int M, int N, int K,
                                               const float* __restrict__ res,
                                               unsigned short* __restrict__ Qh,
                                               unsigned short* __restrict__ Ql,
                                               unsigned short* __restrict__ Kh,
                                               unsigned short* __restrict__ Kl,
                                               unsigned short* __restrict__ Vh,
                                               unsigned short* __restrict__ Vl) {
  __shared__ __align__(16) unsigned short Ash[128 * 32];
  __shared__ __align__(16) unsigned short Asl[128 * 32];
  __shared__ __align__(16) unsigned short Bsh[128 * 32];
  __shared__ __align__(16) unsigned short Bsl[128 * 32];
  const int tid = threadIdx.x;
  const int m0 = blockIdx.y * 128, n0 = blockIdx.x * 128;
  const int lane = tid & 63;
  const int wid = tid >> 6;
  const int wm = (wid >> 1) * 64, wn = (wid & 1) * 64;
  const int fr = lane & 15, fq = lane >> 4;
  const int lr = tid >> 2, lk = (tid & 3) * 8;
  f32x4 acc[4][4] = {};
  const size_t oA0 = (size_t)(m0 + lr) * K + lk, oA1 = (size_t)(m0 + lr + 64) * K + lk;
  const size_t oB0 = (size_t)(n0 + lr) * K + lk, oB1 = (size_t)(n0 + lr + 64) * K + lk;
  const int wb = wid * 512;
  gld16(Ah + oA0, Ash + wb); gld16(Ah + oA1, Ash + wb + 2048);
  gld16(Al + oA0, Asl + wb); gld16(Al + oA1, Asl + wb + 2048);
  gld16(Bh + oB0, Bsh + wb); gld16(Bh + oB1, Bsh + wb + 2048);
  gld16(Bl + oB0, Bsl + wb); gld16(Bl + oB1, Bsl + wb + 2048);
  for (int k0 = 0;;) {
    __syncthreads();
    bf16x8 afh[4], afl[4], bvh[4], bvl[4];
#pragma unroll
    for (int i = 0; i < 4; ++i) {
      afh[i] = *(const bf16x8*)&Ash[(wm + i * 16 + fr) * 32 + fq * 8];
      afl[i] = *(const bf16x8*)&Asl[(wm + i * 16 + fr) * 32 + fq * 8];
    }
#pragma unroll
    for (int j = 0; j < 4; ++j) {
      bvh[j] = *(const bf16x8*)&Bsh[(wn + j * 16 + fr) * 32 + fq * 8];
      bvl[j] = *(const bf16x8*)&Bsl[(wn + j * 16 + fr) * 32 + fq * 8];
    }
    __syncthreads();
    k0 += 32;
    if (k0 < K) {
      gld16(Ah + oA0 + k0, Ash + wb); gld16(Ah + oA1 + k0, Ash + wb + 2048);
      gld16(Al + oA0 + k0, Asl + wb); gld16(Al + oA1 + k0, Asl + wb + 2048);
      gld16(Bh + oB0 + k0, Bsh + wb); gld16(Bh + oB1 + k0, Bsh + wb + 2048);
      gld16(Bl + oB0 + k0, Bsl + wb); gld16(Bl + oB1 + k0, Bsl + wb + 2048);
    }
#pragma unroll
    for (int j = 0; j < 4; ++j) {
#pragma unroll
      for (int i = 0; i < 4; ++i) {
        acc[i][j] = __builtin_amdgcn_mfma_f32_16x16x32_bf16(afl[i], bvh[j], acc[i][j], 0, 0, 0);
        acc[i][j] = __builtin_amdgcn_mfma_f32_16x16x32_bf16(afh[i], bvl[j], acc[i][j], 0, 0, 0);
        acc[i][j] = __builtin_amdgcn_mfma_f32_16x16x32_bf16(afh[i], bvh[j], acc[i][j], 0, 0, 0);
      }
    }
    if (k0 >= K) break;
  }
  if (MODE == 3) {
    // Fused RoPE + hi/lo split. Each (i,reg) holds cols d = fr, fr+16, fr+32, fr+48 of
    // ONE head-band (n0+wn is 64-aligned; 1024%64==0 so band never crosses q/k/v).
    const int band = n0 + wn;
    const int which = band >> 10;           // 0=q 1=k 2=v
    const int h = (band & 1023) >> 6;
    unsigned short* Hp = (which == 0) ? Qh : ((which == 1) ? Kh : Vh);
    unsigned short* Lp = (which == 0) ? Ql : ((which == 1) ? Kl : Vl);
    const float l2t = 13.287712379549449f;  // log2(10000)
    const float inv0 = exp2f(-l2t * (float)fr * (1.0f / 32.0f));
    const float inv1 = exp2f(-l2t * (float)(fr + 16) * (1.0f / 32.0f));
#pragma unroll
    for (int i = 0; i < 4; ++i) {
#pragma unroll
      for (int reg = 0; reg < 4; ++reg) {
        const int row = m0 + wm + i * 16 + fq * 4 + reg;
        const int b = row >> 11, t = row & 2047;
        float o0 = acc[i][0][reg], o1 = acc[i][1][reg];
        float o2 = acc[i][2][reg], o3 = acc[i][3][reg];
        if (which != 2) {
          const float a0 = (float)t * inv0, a1 = (float)t * inv1;
          const float c0 = cosf(a0), sn0 = sinf(a0);
          const float c1 = cosf(a1), sn1 = sinf(a1);
          const float v0 = o0, v1 = o1, v2 = o2, v3 = o3;
          o0 = v0 * c0 - v2 * sn0;   // d = fr        (<32): pair +32 negated
          o1 = v1 * c1 - v3 * sn1;   // d = fr+16
          o2 = v2 * c0 + v0 * sn0;   // d = fr+32     (>=32): pair -32
          o3 = v3 * c1 + v1 * sn1;   // d = fr+48
        }
        const long bo = ((long)((b << 4) + h) * 2048 + t) * 64 + fr;
        const unsigned short h0 = f2bf(o0), h1 = f2bf(o1);
        const unsigned short h2 = f2bf(o2), h3 = f2bf(o3);
        Hp[bo] = h0; Hp[bo + 16] = h1; Hp[bo + 32] = h2; Hp[bo + 48] = h3;
        Lp[bo]      = f2bf(o0 - bf2f(h0));
        Lp[bo + 16] = f2bf(o1 - bf2f(h1));
        Lp[bo + 32] = f2bf(o2 - bf2f(h2));
        Lp[bo + 48] = f2bf(o3 - bf2f(h3));
      }
    }
  } else {
#pragma unroll
    for (int i = 0; i < 4; ++i) {
#pragma unroll
      for (int reg = 0; reg < 4; ++reg) {
        const int row = m0 + wm + i * 16 + fq * 4 + reg;
#pragma unroll
        for (int j = 0; j < 4; ++j) {
          const int col = n0 + wn + j * 16 + fr;
          float* p = C + (size_t)row * N + col;
          if (MODE == 0) *p = acc[i][j][reg];
          else if (MODE == 1) *p += acc[i][j][reg];
          else *p = res[(size_t)row * N + col] + acc[i][j][reg];
        }
      }
    }
  }
}

// ---------------- Split-bf16 MFMA flash attention (router-safe precision) ----------------
__global__ __launch_bounds__(256) void flash_k(const unsigned short* __restrict__ Qhg,
                                               const unsigned short* __restrict__ Qlg,
                                               const unsigned short* __restrict__ Khg,
                                               const unsigned short* __restrict__ Klg,
                                               const unsigned short* __restrict__ Vhg,
                                               const unsigned short* __restrict__ Vlg,
                                               unsigned short* __restrict__ axh,
                                               unsigned short* __restrict__ axl) {
  const int qb = (int)gridDim.x - 1 - (int)blockIdx.x;  // heavy tiles first
  const int bh = blockIdx.y;
  const int b = bh >> 4, h = bh & 15;
  const int q0 = qb << 6;
  __shared__ __align__(16) unsigned short Qsh[64][72];
  __shared__ __align__(16) unsigned short Qsl[64][72];
  __shared__ __align__(16) unsigned short Ksh[64][72];
  __shared__ __align__(16) unsigned short Ksl[64][72];
  __shared__ __align__(16) unsigned short Vth[64][72];  // [d][t]
  __shared__ __align__(16) unsigned short Vtl[64][72];
  __shared__ __align__(16) unsigned short Psh[4][16][72];
  __shared__ __align__(16) unsigned short Psl[4][16][72];
  const int tid = threadIdx.x;
  const int w = tid >> 6;
  const int lane = tid & 63;
  const int fr = lane & 15, fq = lane >> 4;
  const long base_q = ((long)bh * 2048 + q0) * 64;
#pragma unroll
  for (int rep = 0; rep < 2; ++rep) {
    const int f = tid + rep * 256;
    const int r = f >> 3, c8 = (f & 7) * 8;
    *(uint4*)&Qsh[r][c8] = *(const uint4*)(Qhg + base_q + r * 64 + c8);
    *(uint4*)&Qsl[r][c8] = *(const uint4*)(Qlg + base_q + r * 64 + c8);
  }
  f32x4 o_acc[4] = {};
  float m_st[4], l_st[4];
#pragma unroll
  for (int i = 0; i < 4; ++i) { m_st[i] = -3.0e38f; l_st[i] = 0.f; }
  for (int kb = 0; kb <= qb; ++kb) {
    const long base_k = ((long)bh * 2048 + (kb << 6)) * 64;
    __syncthreads();
#pragma unroll
    for (int rep = 0; rep < 2; ++rep) {
      const int f = tid + rep * 256;
      const int r = f >> 3, c8 = (f & 7) * 8;
      *(uint4*)&Ksh[r][c8] = *(const uint4*)(Khg + base_k + r * 64 + c8);
      *(uint4*)&Ksl[r][c8] = *(const uint4*)(Klg + base_k + r * 64 + c8);
    }
#pragma unroll
    for (int rep = 0; rep < 4; ++rep) {
      const int f = tid + rep * 256;
      const int tt = f >> 4, d0 = (f & 15) * 4;
      const ushort4 vh4 = *(const ushort4*)(Vhg + base_k + tt * 64 + d0);
      Vth[d0 + 0][tt] = vh4.x; Vth[d0 + 1][tt] = vh4.y;
      Vth[d0 + 2][tt] = vh4.z; Vth[d0 + 3][tt] = vh4.w;
      const ushort4 vl4 = *(const ushort4*)(Vlg + base_k + tt * 64 + d0);
      Vtl[d0 + 0][tt] = vl4.x; Vtl[d0 + 1][tt] = vl4.y;
      Vtl[d0 + 2][tt] = vl4.z; Vtl[d0 + 3][tt] = vl4.w;
    }
    __syncthreads();
    f32x4 sfr[4] = {};
#pragma unroll
    for (int kc = 0; kc < 2; ++kc) {
      const bf16x8 qh_ = *(const bf16x8*)&Qsh[w * 16 + fr][kc * 32 + fq * 8];
      const bf16x8 ql_ = *(const bf16x8*)&Qsl[w * 16 + fr][kc * 32 + fq * 8];
#pragma unroll
      for (int j = 0; j < 4; ++j) {
        const bf16x8 kh_ = *(const bf16x8*)&Ksh[j * 16 + fr][kc * 32 + fq * 8];
        const bf16x8 kl_ = *(const bf16x8*)&Ksl[j * 16 + fr][kc * 32 + fq * 8];
        sfr[j] = __builtin_amdgcn_mfma_f32_16x16x32_bf16(ql_, kh_, sfr[j], 0, 0, 0);
        sfr[j] = __builtin_amdgcn_mfma_f32_16x16x32_bf16(qh_, kl_, sfr[j], 0, 0, 0);
        sfr[j] = __builtin_amdgcn_mfma_f32_16x16x32_bf16(qh_, kh_, sfr[j], 0, 0, 0);
      }
    }
    const bool diag = (kb == qb);
    float p[4][4];
    float alpha[4];
#pragma unroll
    for (int reg = 0; reg < 4; ++reg) {
      const int qloc = w * 16 + fq * 4 + reg;
      float v[4];
#pragma unroll
      for (int j = 0; j < 4; ++j) {
        float s = sfr[j][reg] * 0.125f;
        if (diag && (j * 16 + fr) > qloc) s = -1.0e30f;
        v[j] = s;
      }
      float mt = fmaxf(fmaxf(v[0], v[1]), fmaxf(v[2], v[3]));
#pragma unroll
      for (int off = 1; off < 16; off <<= 1) mt = fmaxf(mt, __shfl_xor(mt, off));
      const float mn = fmaxf(m_st[reg], mt);
      alpha[reg] = expf(m_st[reg] - mn);
      m_st[reg] = mn;
      float ps = 0.f;
#pragma unroll
      for (int j = 0; j < 4; ++j) { p[j][reg] = expf(v[j] - mn); ps += p[j][reg]; }
#pragma unroll
      for (int off = 1; off < 16; off <<= 1) ps += __shfl_xor(ps, off);
      l_st[reg] = l_st[reg] * alpha[reg] + ps;
    }
#pragma unroll
    for (int reg = 0; reg < 4; ++reg)
#pragma unroll
      for (int j = 0; j < 4; ++j) {
        const float pv = p[j][reg];
        const unsigned short ph = f2bf(pv);
        const unsigned short pl = f2bf(pv - bf2f(ph));
        Psh[w][fq * 4 + reg][j * 16 + fr] = ph;
        Psl[w][fq * 4 + reg][j * 16 + fr] = pl;
      }
#pragma unroll
    for (int j = 0; j < 4; ++j)
#pragma unroll
      for (int reg = 0; reg < 4; ++reg) o_acc[j][reg] *= alpha[reg];
#pragma unroll
    for (int kc = 0; kc < 2; ++kc) {
      const bf16x8 ph_ = *(const bf16x8*)&Psh[w][fr][kc * 32 + fq * 8];
      const bf16x8 pl_ = *(const bf16x8*)&Psl[w][fr][kc * 32 + fq * 8];
#pragma unroll
      for (int j = 0; j < 4; ++j) {
        const bf16x8 vh_ = *(const bf16x8*)&Vth[j * 16 + fr][kc * 32 + fq * 8];
        const bf16x8 vl_ = *(const bf16x8*)&Vtl[j * 16 + fr][kc * 32 + fq * 8];
        o_acc[j] = __builtin_amdgcn_mfma_f32_16x16x32_bf16(pl_, vh_, o_acc[j], 0, 0, 0);
        o_acc[j] = __builtin_amdgcn_mfma_f32_16x16x32_bf16(ph_, vl_, o_acc[j], 0, 0, 0);
        o_acc[j] = __builtin_amdgcn_mfma_f32_16x16x32_bf16(ph_, vh_, o_acc[j], 0, 0, 0);
      }
    }
  }
#pragma unroll
  for (int reg = 0; reg < 4; ++reg) {
    const long tok = (long)b * 2048 + q0 + w * 16 + fq * 4 + reg;
    const float il = 1.f / l_st[reg];
#pragma unroll
    for (int j = 0; j < 4; ++j) {
      const float v = o_acc[j][reg] * il;
      const unsigned short hi = f2bf(v);
      const unsigned short lo = f2bf(v - bf2f(hi));
      const long off = tok * 1024 + h * 64 + j * 16 + fr;
      axh[off] = hi;
      axl[off] = lo;
    }
  }
}

// ---------------- Router: coalesced dot, no atomics, probs to workspace ----------------
__global__ __launch_bounds__(256) void router_k(const float* __restrict__ xn,
                                                const float* __restrict__ rw,
                                                int* __restrict__ topi,
                                                float* __restrict__ topw,
                                                float* __restrict__ probs) {
  const int n = blockIdx.x;
  const int t = threadIdx.x;
  const float4 xv = ((const float4*)(xn + (size_t)n * 1024))[t];
  float acc[16];
#pragma unroll
  for (int e = 0; e < 16; ++e) {
    const float4 wv = ((const float4*)(rw + (size_t)e * 1024))[t];
    acc[e] = xv.x * wv.x + xv.y * wv.y + xv.z * wv.z + xv.w * wv.w;
  }
#pragma unroll
  for (int e = 0; e < 16; ++e)
#pragma unroll
    for (int o = 32; o > 0; o >>= 1) acc[e] += __shfl_down(acc[e], o);
  __shared__ float red[4][16];
  if ((t & 63) == 0) {
#pragma unroll
    for (int e = 0; e < 16; ++e) red[t >> 6][e] = acc[e];
  }
  __syncthreads();
  if (t == 0) {
    float logits[16];
#pragma unroll
    for (int e = 0; e < 16; ++e)
      logits[e] = red[0][e] + red[1][e] + red[2][e] + red[3][e];
    float mx = logits[0];
#pragma unroll
    for (int e = 1; e < 16; ++e) mx = fmaxf(mx, logits[e]);
    float p[16];
    float Z = 0.f;
#pragma unroll
    for (int e = 0; e < 16; ++e) { p[e] = expf(logits[e] - mx); Z += p[e]; }
    const float iz = 1.f / Z;
#pragma unroll
    for (int e = 0; e < 16; ++e) p[e] *= iz;
    int i1 = 0;
#pragma unroll
    for (int e = 1; e < 16; ++e) if (p[e] > p[i1]) i1 = e;
    int i2 = (i1 == 0) ? 1 : 0;
#pragma unroll
    for (int e = 0; e < 16; ++e) if (e != i1 && p[e] > p[i2]) i2 = e;
    const float sw = p[i1] + p[i2];
    topi[2 * n] = i1; topi[2 * n + 1] = i2;
    topw[2 * n] = p[i1] / sw; topw[2 * n + 1] = p[i2] / sw;
    float* pr = probs + (size_t)n * 16;
#pragma unroll
    for (int e = 0; e < 16; ++e) pr[e] = p[e];
  }
}

// ---------------- psum reduction (single block) ----------------
__global__ __launch_bounds__(256) void psum_k(const float* __restrict__ probs,
                                              float* __restrict__ psum) {
  float acc[16] = {};
  for (int n = threadIdx.x; n < 4096; n += 256) {
    const float4* pr = (const float4*)(probs + (size_t)n * 16);
#pragma unroll
    for (int q = 0; q < 4; ++q) {
      const float4 v = pr[q];
      acc[q * 4 + 0] += v.x; acc[q * 4 + 1] += v.y;
      acc[q * 4 + 2] += v.z; acc[q * 4 + 3] += v.w;
    }
  }
#pragma unroll
  for (int e = 0; e < 16; ++e)
#pragma unroll
    for (int o = 32; o > 0; o >>= 1) acc[e] += __shfl_down(acc[e], o);
  __shared__ float red[4][16];
  if ((threadIdx.x & 63) == 0) {
#pragma unroll
    for (int e = 0; e < 16; ++e) red[threadIdx.x >> 6][e] = acc[e];
  }
  __syncthreads();
  if (threadIdx.x < 16)
    psum[threadIdx.x] = red[0][threadIdx.x] + red[1][threadIdx.x] +
                        red[2][threadIdx.x] + red[3][threadIdx.x];
}

// ---------------- Parallel capacity scan (order-exact); also emits cnt ----------------
__global__ __launch_bounds__(256) void pos_k(const int* __restrict__ topi,
                                             const float* __restrict__ topw,
                                             int* __restrict__ slot,
                                             int* __restrict__ keep,
                                             int* __restrict__ s2t,
                                             float* __restrict__ s2w,
                                             float* __restrict__ cnt) {
  __shared__ int fi[8192];
  __shared__ int hist[256][16];
  __shared__ int total[16];
  const int t = threadIdx.x;
  for (int i = t; i < 8192; i += 256) fi[i] = topi[i];
#pragma unroll
  for (int e = 0; e < 16; ++e) hist[t][e] = 0;
  __syncthreads();
  const int base = t * 32;
#pragma unroll 8
  for (int i = 0; i < 32; ++i) hist[t][fi[base + i]]++;
  __syncthreads();
  if (t < 16) {
    int run = 0;
    for (int c = 0; c < 256; ++c) { const int v = hist[c][t]; hist[c][t] = run; run += v; }
    total[t] = run;
    cnt[t] = (float)run;
  }
  __syncthreads();
  int run[16];
#pragma unroll
  for (int e = 0; e < 16; ++e) run[e] = hist[t][e];
  for (int i = 0; i < 32; ++i) {
    const int idx = base + i;
    const int e = fi[idx];
    const int p = run[e]++;
    if (p < 640) {
      slot[idx] = p; keep[idx] = 1;
      s2t[e * 640 + p] = idx >> 1;
      s2w[e * 640 + p] = topw[idx];
    } else {
      slot[idx] = 639; keep[idx] = 0;
    }
  }
  __syncthreads();
  for (int pos = t; pos < 16 * 640; pos += 256) {
    const int e = pos / 640, c = pos - e * 640;
    if (c >= total[e]) s2t[pos] = -1;
  }
}

__global__ __launch_bounds__(128) void scatter_b_k(const unsigned short* __restrict__ xnb,
                                                   const int* __restrict__ topi,
                                                   const int* __restrict__ slot,
                                                   const int* __restrict__ keep,
                                                   unsigned short* __restrict__ buf) {
  const int i = blockIdx.x;
  if (!keep[i]) return;
  const int n = i >> 1;
  const size_t dst = ((size_t)topi[i] * 640 + slot[i]) * 1024;
  ((uint4*)(buf + dst))[threadIdx.x] = ((const uint4*)(xnb + (size_t)n * 1024))[threadIdx.x];
}

__global__ void aux_k(const float* __restrict__ cnt, const float* __restrict__ psum,
                      float* __restrict__ out) {
  if (threadIdx.x == 0) {
    float s = 0.f;
    for (int e = 0; e < 16; ++e)
      s += (cnt[e] * (1.f / 4096.f)) * (psum[e] * (1.f / 4096.f));
    out[0] = 16.f * s;
  }
}

// ---------------- tou softmax (fp32 in -> bf16 probs) + gate ----------------
__global__ __launch_bounds__(256) void softmax512_k(const float* __restrict__ sc,
                                                    unsigned short* __restrict__ out) {
  const long n = blockIdx.x;
  const float2* row = (const float2*)(sc + n * 512);
  const int t = threadIdx.x;
  float2 v = row[t];
  float mx = fmaxf(v.x, v.y);
#pragma unroll
  for (int o = 32; o > 0; o >>= 1) mx = fmaxf(mx, __shfl_down(mx, o));
  __shared__ float red[4];
  __shared__ float bm, bz;
  if ((t & 63) == 0) red[t >> 6] = mx;
  __syncthreads();
  if (t == 0) bm = fmaxf(fmaxf(red[0], red[1]), fmaxf(red[2], red[3]));
  __syncthreads();
  const float M = bm;
  const float e0 = expf(v.x - M), e1 = expf(v.y - M);
  float s = e0 + e1;
#pragma unroll
  for (int o = 32; o > 0; o >>= 1) s += __shfl_down(s, o);
  if ((t & 63) == 0) red[t >> 6] = s;
  __syncthreads();
  if (t == 0) bz = 1.f / (red[0] + red[1] + red[2] + red[3]);
  __syncthreads();
  ushort2 u; u.x = f2bf(e0 * bz); u.y = f2bf(e1 * bz);
  *(ushort2*)(out + n * 512 + t * 2) = u;
}

__global__ __launch_bounds__(256) void gate_k(const float* __restrict__ xn,
                                              const float* __restrict__ gw,
                                              const float* __restrict__ gb,
                                              float* __restrict__ gate) {
  const long n = blockIdx.x;
  const int t = threadIdx.x;
  const float4 v = ((const float4*)(xn + n * 1024))[t];
  const float4 g = ((const float4*)gw)[t];
  float s = v.x * g.x + v.y * g.y + v.z * g.z + v.w * g.w;
#pragma unroll
  for (int o = 32; o > 0; o >>= 1) s += __shfl_down(s, o);
  __shared__ float red[4];
  if ((t & 63) == 0) red[t >> 6] = s;
  __syncthreads();
  if (t == 0) {
    const float tot = red[0] + red[1] + red[2] + red[3] + gb[0];
    gate[n] = 1.f / (1.f + expf(-tot));
  }
}

extern "C" void kernel_launch(void* const* d_in, const int* in_sizes, int n_in,
                              void* d_out, int out_size, void* d_ws, size_t ws_size,
                              hipStream_t stream) {
  (void)in_sizes; (void)n_in; (void)out_size; (void)ws_size;
  const float* x    = (const float*)d_in[0];
  const float* prim = (const float*)d_in[1];
  const float* n1w  = (const float*)d_in[2];
  const float* qkvw = (const float*)d_in[3];
  const float* aow  = (const float*)d_in[4];
  const float* n2w  = (const float*)d_in[5];
  const float* rw   = (const float*)d_in[6];
  const float* w1   = (const float*)d_in[7];
  const float* w2   = (const float*)d_in[8];
  const float* n3w  = (const float*)d_in[9];
  const float* tqw  = (const float*)d_in[10];
  const float* tkw  = (const float*)d_in[11];
  const float* tvw  = (const float*)d_in[12];
  const float* tow  = (const float*)d_in[13];
  const float* tgw  = (const float*)d_in[14];
  const float* tgb  = (const float*)d_in[15];

  float* xbuf = (float*)d_out;
  float* aux  = xbuf + 4194304;

  char* W = (char*)d_ws;
  float* xn            = (float*)W;                           // 16 MB
  unsigned short* xnb  = (unsigned short*)(W + (16u << 20));  // 8 MB (hi)
  unsigned short* xnl  = (unsigned short*)(W + (24u << 20));  // 8 MB (lo)
  char* P = W + (32u << 20);

  // phase A
  unsigned short* qh   = (unsigned short*)(P + (48u << 20));
  unsigned short* ql   = (unsigned short*)(P + (56u << 20));
  unsigned short* kh   = (unsigned short*)(P + (64u << 20));
  unsigned short* kl   = (unsigned short*)(P + (72u << 20));
  unsigned short* vh   = (unsigned short*)(P + (80u << 20));
  unsigned short* vl   = (unsigned short*)(P + (88u << 20));
  unsigned short* axh  = (unsigned short*)(P + (112u << 20));
  unsigned short* axl  = (unsigned short*)(P + (120u << 20));
  unsigned short* qwh  = (unsigned short*)(P + (128u << 20));
  unsigned short* qwl  = (unsigned short*)(P + (134u << 20));
  unsigned short* aoh  = (unsigned short*)(P + (140u << 20));
  unsigned short* aol  = (unsigned short*)(P + (142u << 20));
  // phase B (aliases phase A)
  int*   topi = (int*)P;
  float* topw = (float*)(P + 65536);
  int*   slot = (int*)(P + 131072);
  int*   keep = (int*)(P + 196608);
  float* cnt  = (float*)(P + 262144);
  float* psum = (float*)(P + 262144 + 4096);
  int*   s2t  = (int*)(P + 327680);
  float* s2w  = (float*)(P + 393216);
  float* probs = (float*)(P + 458752);                        // 256 KB
  unsigned short* bufb = (unsigned short*)(P + (1u << 20));   // 21 MB
  unsigned short* hb   = (unsigned short*)(P + (22u << 20));  // 42 MB
  unsigned short* Wt   = (unsigned short*)(P + (64u << 20));  // 67 MB
  // phase C (aliases again)
  unsigned short* tqb  = (unsigned short*)P;
  unsigned short* tkb  = (unsigned short*)(P + (2u << 20));
  unsigned short* tvtb = (unsigned short*)(P + (3u << 20));
  float*          tsc  = (float*)(P + (4u << 20));
  unsigned short* tpb  = (unsigned short*)(P + (12u << 20));
  unsigned short* tavb = (unsigned short*)(P + (16u << 20));
  float*          gate = (float*)(P + (18u << 20));
  unsigned short* tqwb = (unsigned short*)(P + (19u << 20));
  unsigned short* tkwb = (unsigned short*)(P + (20u << 20));
  unsigned short* tvwb = (unsigned short*)(P + (21u << 20));
  unsigned short* towb = (unsigned short*)(P + (22u << 20));
  unsigned short* primb= (unsigned short*)(P + (23u << 20));

  // ---- phase A: x += rope_attention(rmsnorm(x)) ----
  // (no memcpy: O-proj epilogue reads residual x directly and writes xbuf;
  //  RoPE + hi/lo split + [bh][t][dh] transpose fused into the QKV GEMM epilogue)
  rmsnorm_k<0, 1><<<4096, 256, 0, stream>>>(x, n1w, nullptr, xnb, xnl);
  split2_k<<<4096, 256, 0, stream>>>(qkvw, qwh, qwl, aow, aoh, aol);
  bgemm_s<3><<<dim3(24, 32, 1), 256, 0, stream>>>(xnb, xnl, qwh, qwl, nullptr,
      4096, 3072, 1024, nullptr, qh, ql, kh, kl, vh, vl);
  flash_k<<<dim3(32, 32), 256, 0, stream>>>(qh, ql, kh, kl, vh, vl, axh, axl);
  bgemm_s<2><<<dim3(8, 32, 1), 256, 0, stream>>>(axh, axl, aoh, aol, xbuf,
      4096, 1024, 1024, x, nullptr, nullptr, nullptr, nullptr, nullptr, nullptr);

  // ---- phase B: MoE ----
  rmsnorm_k<1, 0><<<4096, 256, 0, stream>>>(xbuf, n2w, xn, xnb, nullptr);
  router_k<<<4096, 256, 0, stream>>>(xn, rw, topi, topw, probs);
  psum_k<<<1, 256, 0, stream>>>(probs, psum);
  pos_k<<<1, 256, 0, stream>>>(topi, topw, slot, keep, s2t, s2w, cnt);
  // no memset of bufb: stale rows beyond cnt[e] are row-independent through both
  // GEMMs and gated off by s2t==-1 in the MODE-5 un-scatter.
  scatter_b_k<<<8192, 128, 0, stream>>>(xnb, topi, slot, keep, bufb);
  cvt_t_k<<<dim3(64, 32, 16), 256, 0, stream>>>(w1, Wt, 1024, 2048);
  bgemm<3><<<dim3(16, 5, 16), 256, 0, stream>>>(bufb, Wt, hb, 640, 2048, 1024,
      (long)640 * 1024, (long)2048 * 1024, (long)640 * 2048, 1.f, nullptr, nullptr, nullptr);
  cvt_t_k<<<dim3(32, 64, 16), 256, 0, stream>>>(w2, Wt, 2048, 1024);
  bgemm<5><<<dim3(8, 5, 16), 256, 0, stream>>>(hb, Wt, xbuf, 640, 1024, 2048,
      (long)640 * 2048, (long)1024 * 2048, 0, 1.f, nullptr, s2t, s2w);
  aux_k<<<1, 64, 0, stream>>>(cnt, psum, aux);

  // ---- phase C: tou cross-attn ----
  rmsnorm_k<1, 0><<<4096, 256, 0, stream>>>(xbuf, n3w, xn, xnb, nullptr);
  cvt5_k<<<768, 256, 0, stream>>>(tqw, tqwb, tkw, tkwb, tvw, tvwb, tow, towb, prim, primb);
  bgemm<2><<<dim3(2, 32, 1), 256, 0, stream>>>(xnb, tqwb, tqb, 4096, 256, 1024, 0, 0, 0, 1.f, nullptr, nullptr, nullptr);
  bgemm<2><<<dim3(2, 4, 1), 256, 0, stream>>>(primb, tkwb, tkb, 512, 256, 256, 0, 0, 0, 1.f, nullptr, nullptr, nullptr);
  bgemm<2><<<dim3(4, 2, 1), 256, 0, stream>>>(tvwb, primb, tvtb, 256, 512, 256, 0, 0, 0, 1.f, nullptr, nullptr, nullptr);
  bgemm<0><<<dim3(4, 32, 1), 256, 0, stream>>>(tqb, tkb, tsc, 4096, 512, 256, 0, 0, 0, 0.0625f, nullptr, nullptr, nullptr);
  softmax512_k<<<4096, 256, 0, stream>>>(tsc, tpb);
  bgemm<2><<<dim3(2, 32, 1), 256, 0, stream>>>(tpb, tvtb, tavb, 4096, 256, 512, 0, 0, 0, 1.f, nullptr, nullptr, nullptr);
  gate_k<<<4096, 256, 0, stream>>>(xn, tgw, tgb, gate);
  bgemm<4><<<dim3(8, 32, 1), 256, 0, stream>>>(tavb, towb, xbuf, 4096, 1024, 256, 0, 0, 0, 1.f, gate, nullptr, nullptr);
}

// Round 3
// 1088.971 us; speedup vs baseline: 1.0671x; 1.0671x over previous
//
#include <hip/hip_runtime.h>
#include <math.h>

// B=2 T=2048 D=1024 H=16 DH=64 E=16 K=2 F=2048 CAP=640 DP=256 NPRIM=512
typedef short bf16x8 __attribute__((ext_vector_type(8)));
typedef float f32x4 __attribute__((ext_vector_type(4)));

__device__ __forceinline__ unsigned short f2bf(float f) {
  union { float f; unsigned u; } v; v.f = f;
  return (unsigned short)((v.u + 0x7fff + ((v.u >> 16) & 1)) >> 16);
}
__device__ __forceinline__ float bf2f(unsigned short h) {
  union { unsigned u; float f; } v; v.u = ((unsigned)h) << 16;
  return v.f;
}

// Direct global->LDS DMA, 16B per lane. LDS dest is wave-uniform base + lane*16.
__device__ __forceinline__ void gld16(const unsigned short* g, unsigned short* l) {
  __builtin_amdgcn_global_load_lds((const __attribute__((address_space(1))) void*)g,
                                   (__attribute__((address_space(3))) void*)l, 16, 0, 0);
}

// ---------------- RMSNorm: optional fp32 out, bf16-hi out, optional bf16-lo out ----------------
template <int WF32, int WLO>
__global__ __launch_bounds__(256) void rmsnorm_k(const float* __restrict__ x,
                                                 const float* __restrict__ w,
                                                 float* __restrict__ y,
                                                 unsigned short* __restrict__ yb,
                                                 unsigned short* __restrict__ yl) {
  const long n = blockIdx.x;
  const int t = threadIdx.x;
  const float4 v = ((const float4*)(x + n * 1024))[t];
  float ss = v.x * v.x + v.y * v.y + v.z * v.z + v.w * v.w;
#pragma unroll
  for (int o = 32; o > 0; o >>= 1) ss += __shfl_down(ss, o);
  __shared__ float red[4];
  __shared__ float sc;
  if ((t & 63) == 0) red[t >> 6] = ss;
  __syncthreads();
  if (t == 0) sc = rsqrtf((red[0] + red[1] + red[2] + red[3]) * (1.0f / 1024.0f) + 1e-6f);
  __syncthreads();
  const float s = sc;
  const float4 wv = ((const float4*)w)[t];
  float4 o;
  o.x = v.x * s * wv.x; o.y = v.y * s * wv.y; o.z = v.z * s * wv.z; o.w = v.w * s * wv.w;
  if (WF32) ((float4*)(y + n * 1024))[t] = o;
  ushort4 u = make_ushort4(f2bf(o.x), f2bf(o.y), f2bf(o.z), f2bf(o.w));
  *(ushort4*)(yb + n * 1024 + t * 4) = u;
  if (WLO) {
    ushort4 l = make_ushort4(f2bf(o.x - bf2f(u.x)), f2bf(o.y - bf2f(u.y)),
                             f2bf(o.z - bf2f(u.z)), f2bf(o.w - bf2f(u.w)));
    *(ushort4*)(yl + n * 1024 + t * 4) = l;
  }
}

// ---------------- fused weight hi/lo splits: qkvw (786432 f4) + aow (262144 f4) ----------------
__global__ __launch_bounds__(256) void split2_k(const float* __restrict__ s0,
                                                unsigned short* __restrict__ h0,
                                                unsigned short* __restrict__ l0,
                                                const float* __restrict__ s1,
                                                unsigned short* __restrict__ h1,
                                                unsigned short* __restrict__ l1) {
  const int i = blockIdx.x * 256 + threadIdx.x;  // 4096*256 = 1048576 float4 groups
  const float* s; unsigned short* hp; unsigned short* lp; int off;
  if (i < 786432) { s = s0; hp = h0; lp = l0; off = i; }
  else            { s = s1; hp = h1; lp = l1; off = i - 786432; }
  const float4 v = ((const float4*)s)[off];
  ushort4 h = make_ushort4(f2bf(v.x), f2bf(v.y), f2bf(v.z), f2bf(v.w));
  ushort4 l = make_ushort4(f2bf(v.x - bf2f(h.x)), f2bf(v.y - bf2f(h.y)),
                           f2bf(v.z - bf2f(h.z)), f2bf(v.w - bf2f(h.w)));
  ((ushort4*)hp)[off] = h;
  ((ushort4*)lp)[off] = l;
}

// ---------------- fused phase-C weight conversions (5 regions, 1 launch) ----------------
__global__ __launch_bounds__(256) void cvt5_k(const float* __restrict__ s0, unsigned short* __restrict__ d0,
                                              const float* __restrict__ s1, unsigned short* __restrict__ d1,
                                              const float* __restrict__ s2, unsigned short* __restrict__ d2,
                                              const float* __restrict__ s3, unsigned short* __restrict__ d3,
                                              const float* __restrict__ s4, unsigned short* __restrict__ d4) {
  const int i = blockIdx.x * 256 + threadIdx.x;  // 768*256 = 196608 float4 groups total
  const float* s; unsigned short* d; int off;
  if (i < 65536)       { s = s0; d = d0; off = i; }
  else if (i < 81920)  { s = s1; d = d1; off = i - 65536; }
  else if (i < 98304)  { s = s2; d = d2; off = i - 81920; }
  else if (i < 163840) { s = s3; d = d3; off = i - 98304; }
  else                 { s = s4; d = d4; off = i - 163840; }
  const float4 v = ((const float4*)s)[off];
  ((ushort4*)d)[off] = make_ushort4(f2bf(v.x), f2bf(v.y), f2bf(v.z), f2bf(v.w));
}

// ---------------- transpose-convert: (R,C) fp32 -> (C,R) bf16, batched ----------------
__global__ __launch_bounds__(256) void cvt_t_k(const float* __restrict__ in,
                                               unsigned short* __restrict__ out,
                                               int R, int C) {
  in += (size_t)blockIdx.z * R * C;
  out += (size_t)blockIdx.z * R * C;
  const int r0 = blockIdx.y * 32, c0 = blockIdx.x * 32;
  __shared__ float T[32][33];
  const int tid = threadIdx.x;
  const int li = tid >> 3;
  const int lj = (tid & 7) << 2;
  const float4 v = *(const float4*)(in + (size_t)(r0 + li) * C + c0 + lj);
  T[li][lj + 0] = v.x; T[li][lj + 1] = v.y; T[li][lj + 2] = v.z; T[li][lj + 3] = v.w;
  __syncthreads();
  ushort4 u = make_ushort4(f2bf(T[lj + 0][li]), f2bf(T[lj + 1][li]),
                           f2bf(T[lj + 2][li]), f2bf(T[lj + 3][li]));
  *(ushort4*)(out + (size_t)(c0 + li) * R + r0 + lj) = u;
}

// ---------------- bf16 MFMA GEMM: C(M,N) = alpha * A(M,K) x B(N,K)^T ----------------
// m97 structure: linear LDS + global_load_lds width-16 staging (no reg round-trip).
// MODE: 0=f32 store, 1=f32 +=, 2=bf16 store, 3=bf16 silu store,
//       4=f32 += rowscale[row]*v, 5=f32 atomicAdd to rowmap token (MoE un-scatter)
template <int MODE>
__global__ __launch_bounds__(256) void bgemm(const unsigned short* __restrict__ A,
                                             const unsigned short* __restrict__ B,
                                             void* __restrict__ Cv,
                                             int M, int N, int K,
                                             long sA, long sB, long sC, float alpha,
                                             const float* __restrict__ rowscale,
                                             const int* __restrict__ rowmap,
                                             const float* __restrict__ roww) {
  __shared__ __align__(16) unsigned short As[128 * 32];
  __shared__ __align__(16) unsigned short Bs[128 * 32];
  const int tid = threadIdx.x;
  const int z = blockIdx.z;
  const unsigned short* Ag = A + (size_t)z * sA;
  const unsigned short* Bg = B + (size_t)z * sB;
  const int m0 = blockIdx.y * 128, n0 = blockIdx.x * 128;
  const int lane = tid & 63;
  const int wid = tid >> 6;
  const int wm = (wid >> 1) * 64, wn = (wid & 1) * 64;
  const int fr = lane & 15, fq = lane >> 4;
  const int lr = tid >> 2, lk = (tid & 3) * 8;
  f32x4 acc[4][4] = {};
  const unsigned short* Ap0 = Ag + (size_t)(m0 + lr) * K + lk;
  const unsigned short* Ap1 = Ag + (size_t)(m0 + lr + 64) * K + lk;
  const unsigned short* Bp0 = Bg + (size_t)(n0 + lr) * K + lk;
  const unsigned short* Bp1 = Bg + (size_t)(n0 + lr + 64) * K + lk;
  unsigned short* Asw = As + wid * 512;  // wave-uniform LDS base (bytes: wid*1024)
  unsigned short* Bsw = Bs + wid * 512;
  gld16(Ap0, Asw); gld16(Ap1, Asw + 2048);
  gld16(Bp0, Bsw); gld16(Bp1, Bsw + 2048);
  for (int k0 = 0;;) {
    __syncthreads();  // drains vmcnt: staged tile visible to all waves
    bf16x8 af[4], bv[4];
#pragma unroll
    for (int i = 0; i < 4; ++i) af[i] = *(const bf16x8*)&As[(wm + i * 16 + fr) * 32 + fq * 8];
#pragma unroll
    for (int j = 0; j < 4; ++j) bv[j] = *(const bf16x8*)&Bs[(wn + j * 16 + fr) * 32 + fq * 8];
    __syncthreads();  // all frag reads done -> safe to overwrite tile
    k0 += 32;
    if (k0 < K) {     // next-tile DMA overlaps the MFMAs below
      gld16(Ap0 + k0, Asw); gld16(Ap1 + k0, Asw + 2048);
      gld16(Bp0 + k0, Bsw); gld16(Bp1 + k0, Bsw + 2048);
    }
#pragma unroll
    for (int i = 0; i < 4; ++i)
#pragma unroll
      for (int j = 0; j < 4; ++j)
        acc[i][j] = __builtin_amdgcn_mfma_f32_16x16x32_bf16(af[i], bv[j], acc[i][j], 0, 0, 0);
    if (k0 >= K) break;
  }
#pragma unroll
  for (int i = 0; i < 4; ++i) {
#pragma unroll
    for (int reg = 0; reg < 4; ++reg) {
      const int row = m0 + wm + i * 16 + fq * 4 + reg;
      float rs = 0.f, wgt = 0.f;
      int tok = -1;
      if (MODE == 4) rs = rowscale[row];
      if (MODE == 5) {
        tok = rowmap[z * M + row];
        if (tok >= 0) wgt = roww[z * M + row];
      }
#pragma unroll
      for (int j = 0; j < 4; ++j) {
        const int col = n0 + wn + j * 16 + fr;
        const float v = alpha * acc[i][j][reg];
        if (MODE == 0) {
          ((float*)Cv + (size_t)z * sC)[(size_t)row * N + col] = v;
        } else if (MODE == 1) {
          float* p = (float*)Cv + (size_t)z * sC + (size_t)row * N + col;
          *p += v;
        } else if (MODE == 2) {
          ((unsigned short*)Cv + (size_t)z * sC)[(size_t)row * N + col] = f2bf(v);
        } else if (MODE == 3) {
          const float sv = v / (1.f + expf(-v));
          ((unsigned short*)Cv + (size_t)z * sC)[(size_t)row * N + col] = f2bf(sv);
        } else if (MODE == 4) {
          float* p = (float*)Cv + (size_t)row * N + col;
          *p += rs * v;
        } else if (MODE == 5) {
          if (tok >= 0) atomicAdd((float*)Cv + (size_t)tok * N + col, wgt * v);
        }
      }
    }
  }
}

// ---------------- Fused split-bf16 GEMM: C = (Ah+Al)(Bh+Bl)^T (3-term) ----------------
// MODE: 0 = f32 store, 1 = f32 +=, 2 = f32 store of res[row,col] + v (residual fuse),
//       3 = fused RoPE + hi/lo split QKV output to [bh][t][dh] (no C)
template <int MODE>
__global__ __launch_bounds__(256) void bgemm_s(const unsigned short* __restrict__ Ah,
                                               const unsigned short* __restrict__ Al,
                                               const unsigned short* __restrict__ Bh,
                                               const unsigned short* __restrict__ Bl,
                                               float* __restrict__ C,
                                               int M, int N, int K,
                                               const float* __restrict__ res,
                                               unsigned short* __restrict__ Qh,
                                               unsigned short* __restrict__ Ql,
                                               unsigned short* __restrict__ Kh,
                                               unsigned short* __restrict__ Kl,
                                               unsigned short* __restrict__ Vh,
                                               unsigned short* __restrict__ Vl) {
  __shared__ __align__(16) unsigned short Ash[128 * 32];
  __shared__ __align__(16) unsigned short Asl[128 * 32];
  __shared__ __align__(16) unsigned short Bsh[128 * 32];
  __shared__ __align__(16) unsigned short Bsl[128 * 32];
  const int tid = threadIdx.x;
  const int m0 = blockIdx.y * 128, n0 = blockIdx.x * 128;
  const int lane = tid & 63;
  const int wid = tid >> 6;
  const int wm = (wid >> 1) * 64, wn = (wid & 1) * 64;
  const int fr = lane & 15, fq = lane >> 4;
  const int lr = tid >> 2, lk = (tid & 3) * 8;
  f32x4 acc[4][4] = {};
  const size_t oA0 = (size_t)(m0 + lr) * K + lk, oA1 = (size_t)(m0 + lr + 64) * K + lk;
  const size_t oB0 = (size_t)(n0 + lr) * K + lk, oB1 = (size_t)(n0 + lr + 64) * K + lk;
  const int wb = wid * 512;
  gld16(Ah + oA0, Ash + wb); gld16(Ah + oA1, Ash + wb + 2048);
  gld16(Al + oA0, Asl + wb); gld16(Al + oA1, Asl + wb + 2048);
  gld16(Bh + oB0, Bsh + wb); gld16(Bh + oB1, Bsh + wb + 2048);
  gld16(Bl + oB0, Bsl + wb); gld16(Bl + oB1, Bsl + wb + 2048);
  for (int k0 = 0;;) {
    __syncthreads();
    bf16x8 afh[4], afl[4], bvh[4], bvl[4];
#pragma unroll
    for (int i = 0; i < 4; ++i) {
      afh[i] = *(const bf16x8*)&Ash[(wm + i * 16 + fr) * 32 + fq * 8];
      afl[i] = *(const bf16x8*)&Asl[(wm + i * 16 + fr) * 32 + fq * 8];
    }
#pragma unroll
    for (int j = 0; j < 4; ++j) {
      bvh[j] = *(const bf16x8*)&Bsh[(wn + j * 16 + fr) * 32 + fq * 8];
      bvl[j] = *(const bf16x8*)&Bsl[(wn + j * 16 + fr) * 32 + fq * 8];
    }
    __syncthreads();
    k0 += 32;
    if (k0 < K) {
      gld16(Ah + oA0 + k0, Ash + wb); gld16(Ah + oA1 + k0, Ash + wb + 2048);
      gld16(Al + oA0 + k0, Asl + wb); gld16(Al + oA1 + k0, Asl + wb + 2048);
      gld16(Bh + oB0 + k0, Bsh + wb); gld16(Bh + oB1 + k0, Bsh + wb + 2048);
      gld16(Bl + oB0 + k0, Bsl + wb); gld16(Bl + oB1 + k0, Bsl + wb + 2048);
    }
#pragma unroll
    for (int j = 0; j < 4; ++j) {
#pragma unroll
      for (int i = 0; i < 4; ++i) {
        acc[i][j] = __builtin_amdgcn_mfma_f32_16x16x32_bf16(afl[i], bvh[j], acc[i][j], 0, 0, 0);
        acc[i][j] = __builtin_amdgcn_mfma_f32_16x16x32_bf16(afh[i], bvl[j], acc[i][j], 0, 0, 0);
        acc[i][j] = __builtin_amdgcn_mfma_f32_16x16x32_bf16(afh[i], bvh[j], acc[i][j], 0, 0, 0);
      }
    }
    if (k0 >= K) break;
  }
  if (MODE == 3) {
    // Fused RoPE + hi/lo split. Each (i,reg) holds cols d = fr, fr+16, fr+32, fr+48 of
    // ONE head-band (n0+wn is 64-aligned; 1024%64==0 so band never crosses q/k/v).
    const int band = n0 + wn;
    const int which = band >> 10;           // 0=q 1=k 2=v
    const int h = (band & 1023) >> 6;
    unsigned short* Hp = (which == 0) ? Qh : ((which == 1) ? Kh : Vh);
    unsigned short* Lp = (which == 0) ? Ql : ((which == 1) ? Kl : Vl);
    const float l2t = 13.287712379549449f;  // log2(10000)
    const float inv0 = exp2f(-l2t * (float)fr * (1.0f / 32.0f));
    const float inv1 = exp2f(-l2t * (float)(fr + 16) * (1.0f / 32.0f));
#pragma unroll
    for (int i = 0; i < 4; ++i) {
#pragma unroll
      for (int reg = 0; reg < 4; ++reg) {
        const int row = m0 + wm + i * 16 + fq * 4 + reg;
        const int b = row >> 11, t = row & 2047;
        float o0 = acc[i][0][reg], o1 = acc[i][1][reg];
        float o2 = acc[i][2][reg], o3 = acc[i][3][reg];
        if (which != 2) {
          const float a0 = (float)t * inv0, a1 = (float)t * inv1;
          const float c0 = cosf(a0), sn0 = sinf(a0);
          const float c1 = cosf(a1), sn1 = sinf(a1);
          const float v0 = o0, v1 = o1, v2 = o2, v3 = o3;
          o0 = v0 * c0 - v2 * sn0;   // d = fr        (<32): pair +32 negated
          o1 = v1 * c1 - v3 * sn1;   // d = fr+16
          o2 = v2 * c0 + v0 * sn0;   // d = fr+32     (>=32): pair -32
          o3 = v3 * c1 + v1 * sn1;   // d = fr+48
        }
        const long bo = ((long)((b << 4) + h) * 2048 + t) * 64 + fr;
        const unsigned short h0 = f2bf(o0), h1 = f2bf(o1);
        const unsigned short h2 = f2bf(o2), h3 = f2bf(o3);
        Hp[bo] = h0; Hp[bo + 16] = h1; Hp[bo + 32] = h2; Hp[bo + 48] = h3;
        Lp[bo]      = f2bf(o0 - bf2f(h0));
        Lp[bo + 16] = f2bf(o1 - bf2f(h1));
        Lp[bo + 32] = f2bf(o2 - bf2f(h2));
        Lp[bo + 48] = f2bf(o3 - bf2f(h3));
      }
    }
  } else {
#pragma unroll
    for (int i = 0; i < 4; ++i) {
#pragma unroll
      for (int reg = 0; reg < 4; ++reg) {
        const int row = m0 + wm + i * 16 + fq * 4 + reg;
#pragma unroll
        for (int j = 0; j < 4; ++j) {
          const int col = n0 + wn + j * 16 + fr;
          float* p = C + (size_t)row * N + col;
          if (MODE == 0) *p = acc[i][j][reg];
          else if (MODE == 1) *p += acc[i][j][reg];
          else *p = res[(size_t)row * N + col] + acc[i][j][reg];
        }
      }
    }
  }
}

// ---------------- Split-bf16 MFMA flash attention, v2 ----------------
// Occupancy: LDS 48KB -> 3 blocks/CU (was 72KB -> 2). Q in registers.
// XOR-swizzled [64][64] tiles: element (r,c) at shorts r*64 + (c ^ ((r&7)<<3)) chunk-wise.
// K staged by global_load_lds with pre-swizzled SOURCE (linear LDS dest);
// V staged global->reg early (latency hidden under softmax/PV), written post-barrier.
__global__ __launch_bounds__(256) void flash_k(const unsigned short* __restrict__ Qhg,
                                               const unsigned short* __restrict__ Qlg,
                                               const unsigned short* __restrict__ Khg,
                                               const unsigned short* __restrict__ Klg,
                                               const unsigned short* __restrict__ Vhg,
                                               const unsigned short* __restrict__ Vlg,
                                               unsigned short* __restrict__ axh,
                                               unsigned short* __restrict__ axl) {
  const int qb = (int)gridDim.x - 1 - (int)blockIdx.x;  // heavy tiles first
  const int bh = blockIdx.y;
  const int b = bh >> 4, h = bh & 15;
  const int q0 = qb << 6;
  __shared__ __align__(16) unsigned short Ksh[64 * 64];
  __shared__ __align__(16) unsigned short Ksl[64 * 64];
  __shared__ __align__(16) unsigned short Vth[64 * 64];  // V^T: row d, col t
  __shared__ __align__(16) unsigned short Vtl[64 * 64];
  __shared__ __align__(16) unsigned short Psh[4 * 16 * 64];
  __shared__ __align__(16) unsigned short Psl[4 * 16 * 64];
  const int tid = threadIdx.x;
  const int w = tid >> 6;
  const int lane = tid & 63;
  const int fr = lane & 15, fq = lane >> 4;
  const long base_q = ((long)bh * 2048 + q0) * 64;
  // Q in registers (per-wave static fragments)
  bf16x8 qh_r[2], ql_r[2];
#pragma unroll
  for (int kc = 0; kc < 2; ++kc) {
    qh_r[kc] = *(const bf16x8*)(Qhg + base_q + (w * 16 + fr) * 64 + kc * 32 + fq * 8);
    ql_r[kc] = *(const bf16x8*)(Qlg + base_q + (w * 16 + fr) * 64 + kc * 32 + fq * 8);
  }
  f32x4 o_acc[4] = {};
  float m_st[4], l_st[4];
#pragma unroll
  for (int i = 0; i < 4; ++i) { m_st[i] = -3.0e38f; l_st[i] = 0.f; }

  uint4 vhr[2], vlr[2];  // V prefetch registers (2 reps x hi/lo)

  // ---- prologue: stage tile 0 ----
  {
    const long bk = (long)bh * 2048 * 64;  // kb = 0
#pragma unroll
    for (int rep = 0; rep < 2; ++rep) {
      const int f = tid + rep * 256;
      const int r = f >> 3, c = f & 7;
      const long src = bk + r * 64 + ((c ^ (r & 7)) * 8);  // pre-swizzled source chunk
      gld16(Khg + src, Ksh + f * 8);
      gld16(Klg + src, Ksl + f * 8);
    }
#pragma unroll
    for (int rep = 0; rep < 2; ++rep) {
      const int f = tid + rep * 256;
      const int t = f >> 3, d0 = (f & 7) * 8;
      vhr[rep] = *(const uint4*)(Vhg + bk + t * 64 + d0);
      vlr[rep] = *(const uint4*)(Vlg + bk + t * 64 + d0);
    }
#pragma unroll
    for (int rep = 0; rep < 2; ++rep) {
      const int f = tid + rep * 256;
      const int t = f >> 3, d0 = (f & 7) * 8;
      unsigned uh[4] = {vhr[rep].x, vhr[rep].y, vhr[rep].z, vhr[rep].w};
      unsigned ul[4] = {vlr[rep].x, vlr[rep].y, vlr[rep].z, vlr[rep].w};
#pragma unroll
      for (int i2 = 0; i2 < 4; ++i2) {
        const int de = d0 + 2 * i2, doo = de + 1;
        Vth[de * 64 + (t ^ ((2 * i2) << 3))] = (unsigned short)(uh[i2] & 0xffff);
        Vth[doo * 64 + (t ^ ((2 * i2 + 1) << 3))] = (unsigned short)(uh[i2] >> 16);
        Vtl[de * 64 + (t ^ ((2 * i2) << 3))] = (unsigned short)(ul[i2] & 0xffff);
        Vtl[doo * 64 + (t ^ ((2 * i2 + 1) << 3))] = (unsigned short)(ul[i2] >> 16);
      }
    }
    __syncthreads();  // drains K DMA (vmcnt) + V writes (lgkmcnt)
  }

  for (int kb = 0;; ++kb) {
    const bool more = (kb < qb);
    const long bk_next = ((long)bh * 2048 + ((kb + 1) << 6)) * 64;
    // ---- 1. QK^T (reads Ksh/Ksl + Q regs) ----
    f32x4 sfr[4] = {};
    __builtin_amdgcn_s_setprio(1);
#pragma unroll
    for (int kc = 0; kc < 2; ++kc) {
#pragma unroll
      for (int j = 0; j < 4; ++j) {
        const int co = (j * 16 + fr) * 64 + ((kc * 32 + fq * 8) ^ ((fr & 7) << 3));
        const bf16x8 kh_ = *(const bf16x8*)&Ksh[co];
        const bf16x8 kl_ = *(const bf16x8*)&Ksl[co];
        sfr[j] = __builtin_amdgcn_mfma_f32_16x16x32_bf16(ql_r[kc], kh_, sfr[j], 0, 0, 0);
        sfr[j] = __builtin_amdgcn_mfma_f32_16x16x32_bf16(qh_r[kc], kl_, sfr[j], 0, 0, 0);
        sfr[j] = __builtin_amdgcn_mfma_f32_16x16x32_bf16(qh_r[kc], kh_, sfr[j], 0, 0, 0);
      }
    }
    __builtin_amdgcn_s_setprio(0);
    // ---- 2. prefetch next V into regs (latency hides under softmax + PV) ----
    if (more) {
#pragma unroll
      for (int rep = 0; rep < 2; ++rep) {
        const int f = tid + rep * 256;
        const int t = f >> 3, d0 = (f & 7) * 8;
        vhr[rep] = *(const uint4*)(Vhg + bk_next + t * 64 + d0);
        vlr[rep] = *(const uint4*)(Vlg + bk_next + t * 64 + d0);
      }
    }
    // ---- 3. online softmax + P -> LDS (per-wave region, no cross-wave sync) ----
    const bool diag = (kb == qb);
    float p[4][4];
    float alpha[4];
#pragma unroll
    for (int reg = 0; reg < 4; ++reg) {
      const int qloc = w * 16 + fq * 4 + reg;
      float v[4];
#pragma unroll
      for (int j = 0; j < 4; ++j) {
        float s = sfr[j][reg] * 0.125f;
        if (diag && (j * 16 + fr) > qloc) s = -1.0e30f;
        v[j] = s;
      }
      float mt = fmaxf(fmaxf(v[0], v[1]), fmaxf(v[2], v[3]));
#pragma unroll
      for (int off = 1; off < 16; off <<= 1) mt = fmaxf(mt, __shfl_xor(mt, off));
      const float mn = fmaxf(m_st[reg], mt);
      alpha[reg] = expf(m_st[reg] - mn);
      m_st[reg] = mn;
      float ps = 0.f;
#pragma unroll
      for (int j = 0; j < 4; ++j) { p[j][reg] = expf(v[j] - mn); ps += p[j][reg]; }
#pragma unroll
      for (int off = 1; off < 16; off <<= 1) ps += __shfl_xor(ps, off);
      l_st[reg] = l_st[reg] * alpha[reg] + ps;
    }
#pragma unroll
    for (int reg = 0; reg < 4; ++reg) {
      const int qp = fq * 4 + reg;
#pragma unroll
      for (int j = 0; j < 4; ++j) {
        const float pv = p[j][reg];
        const unsigned short ph = f2bf(pv);
        const unsigned short pl = f2bf(pv - bf2f(ph));
        const int sa = w * 1024 + qp * 64 + ((j * 16 + fr) ^ ((qp & 7) << 3));
        Psh[sa] = ph;
        Psl[sa] = pl;
      }
    }
#pragma unroll
    for (int j = 0; j < 4; ++j)
#pragma unroll
      for (int reg = 0; reg < 4; ++reg) o_acc[j][reg] *= alpha[reg];
    // ---- 4. barrier: all waves done reading K(kb) ----
    __syncthreads();
    // ---- 5. issue K(kb+1) DMA (completes under PV; drained at barrier 7) ----
    if (more) {
#pragma unroll
      for (int rep = 0; rep < 2; ++rep) {
        const int f = tid + rep * 256;
        const int r = f >> 3, c = f & 7;
        const long src = bk_next + r * 64 + ((c ^ (r & 7)) * 8);
        gld16(Khg + src, Ksh + f * 8);
        gld16(Klg + src, Ksl + f * 8);
      }
    }
    // ---- 6. PV (reads Vth/Vtl + Psh/Psl) ----
    __builtin_amdgcn_s_setprio(1);
#pragma unroll
    for (int kc = 0; kc < 2; ++kc) {
      const int po = w * 1024 + fr * 64 + ((kc * 32 + fq * 8) ^ ((fr & 7) << 3));
      const bf16x8 ph_ = *(const bf16x8*)&Psh[po];
      const bf16x8 pl_ = *(const bf16x8*)&Psl[po];
#pragma unroll
      for (int j = 0; j < 4; ++j) {
        const int co = (j * 16 + fr) * 64 + ((kc * 32 + fq * 8) ^ ((fr & 7) << 3));
        const bf16x8 vh_ = *(const bf16x8*)&Vth[co];
        const bf16x8 vl_ = *(const bf16x8*)&Vtl[co];
        o_acc[j] = __builtin_amdgcn_mfma_f32_16x16x32_bf16(pl_, vh_, o_acc[j], 0, 0, 0);
        o_acc[j] = __builtin_amdgcn_mfma_f32_16x16x32_bf16(ph_, vl_, o_acc[j], 0, 0, 0);
        o_acc[j] = __builtin_amdgcn_mfma_f32_16x16x32_bf16(ph_, vh_, o_acc[j], 0, 0, 0);
      }
    }
    __builtin_amdgcn_s_setprio(0);
    if (!more) break;
    // ---- 7. barrier: all waves done reading V(kb); K DMA drained ----
    __syncthreads();
    // ---- 8. write V(kb+1) from prefetch regs ----
#pragma unroll
    for (int rep = 0; rep < 2; ++rep) {
      const int f = tid + rep * 256;
      const int t = f >> 3, d0 = (f & 7) * 8;
      unsigned uh[4] = {vhr[rep].x, vhr[rep].y, vhr[rep].z, vhr[rep].w};
      unsigned ul[4] = {vlr[rep].x, vlr[rep].y, vlr[rep].z, vlr[rep].w};
#pragma unroll
      for (int i2 = 0; i2 < 4; ++i2) {
        const int de = d0 + 2 * i2, doo = de + 1;
        Vth[de * 64 + (t ^ ((2 * i2) << 3))] = (unsigned short)(uh[i2] & 0xffff);
        Vth[doo * 64 + (t ^ ((2 * i2 + 1) << 3))] = (unsigned short)(uh[i2] >> 16);
        Vtl[de * 64 + (t ^ ((2 * i2) << 3))] = (unsigned short)(ul[i2] & 0xffff);
        Vtl[doo * 64 + (t ^ ((2 * i2 + 1) << 3))] = (unsigned short)(ul[i2] >> 16);
      }
    }
    // next iteration's QK reads K(kb+1): DMA was drained at barrier 7; V writes for
    // (kb+1) are per-wave and guarded from other waves' PV by barrier 4 of kb+1.
  }
#pragma unroll
  for (int reg = 0; reg < 4; ++reg) {
    const long tok = (long)b * 2048 + q0 + w * 16 + fq * 4 + reg;
    const float il = 1.f / l_st[reg];
#pragma unroll
    for (int j = 0; j < 4; ++j) {
      const float v = o_acc[j][reg] * il;
      const unsigned short hi = f2bf(v);
      const unsigned short lo = f2bf(v - bf2f(hi));
      const long off = tok * 1024 + h * 64 + j * 16 + fr;
      axh[off] = hi;
      axl[off] = lo;
    }
  }
}

// ---------------- Router: coalesced dot, no atomics, probs to workspace ----------------
__global__ __launch_bounds__(256) void router_k(const float* __restrict__ xn,
                                                const float* __restrict__ rw,
                                                int* __restrict__ topi,
                                                float* __restrict__ topw,
                                                float* __restrict__ probs) {
  const int n = blockIdx.x;
  const int t = threadIdx.x;
  const float4 xv = ((const float4*)(xn + (size_t)n * 1024))[t];
  float acc[16];
#pragma unroll
  for (int e = 0; e < 16; ++e) {
    const float4 wv = ((const float4*)(rw + (size_t)e * 1024))[t];
    acc[e] = xv.x * wv.x + xv.y * wv.y + xv.z * wv.z + xv.w * wv.w;
  }
#pragma unroll
  for (int e = 0; e < 16; ++e)
#pragma unroll
    for (int o = 32; o > 0; o >>= 1) acc[e] += __shfl_down(acc[e], o);
  __shared__ float red[4][16];
  if ((t & 63) == 0) {
#pragma unroll
    for (int e = 0; e < 16; ++e) red[t >> 6][e] = acc[e];
  }
  __syncthreads();
  if (t == 0) {
    float logits[16];
#pragma unroll
    for (int e = 0; e < 16; ++e)
      logits[e] = red[0][e] + red[1][e] + red[2][e] + red[3][e];
    float mx = logits[0];
#pragma unroll
    for (int e = 1; e < 16; ++e) mx = fmaxf(mx, logits[e]);
    float p[16];
    float Z = 0.f;
#pragma unroll
    for (int e = 0; e < 16; ++e) { p[e] = expf(logits[e] - mx); Z += p[e]; }
    const float iz = 1.f / Z;
#pragma unroll
    for (int e = 0; e < 16; ++e) p[e] *= iz;
    int i1 = 0;
#pragma unroll
    for (int e = 1; e < 16; ++e) if (p[e] > p[i1]) i1 = e;
    int i2 = (i1 == 0) ? 1 : 0;
#pragma unroll
    for (int e = 0; e < 16; ++e) if (e != i1 && p[e] > p[i2]) i2 = e;
    const float sw = p[i1] + p[i2];
    topi[2 * n] = i1; topi[2 * n + 1] = i2;
    topw[2 * n] = p[i1] / sw; topw[2 * n + 1] = p[i2] / sw;
    float* pr = probs + (size_t)n * 16;
#pragma unroll
    for (int e = 0; e < 16; ++e) pr[e] = p[e];
  }
}

// ---------------- psum reduction (single block) ----------------
__global__ __launch_bounds__(256) void psum_k(const float* __restrict__ probs,
                                              float* __restrict__ psum) {
  float acc[16] = {};
  for (int n = threadIdx.x; n < 4096; n += 256) {
    const float4* pr = (const float4*)(probs + (size_t)n * 16);
#pragma unroll
    for (int q = 0; q < 4; ++q) {
      const float4 v = pr[q];
      acc[q * 4 + 0] += v.x; acc[q * 4 + 1] += v.y;
      acc[q * 4 + 2] += v.z; acc[q * 4 + 3] += v.w;
    }
  }
#pragma unroll
  for (int e = 0; e < 16; ++e)
#pragma unroll
    for (int o = 32; o > 0; o >>= 1) acc[e] += __shfl_down(acc[e], o);
  __shared__ float red[4][16];
  if ((threadIdx.x & 63) == 0) {
#pragma unroll
    for (int e = 0; e < 16; ++e) red[threadIdx.x >> 6][e] = acc[e];
  }
  __syncthreads();
  if (threadIdx.x < 16)
    psum[threadIdx.x] = red[0][threadIdx.x] + red[1][threadIdx.x] +
                        red[2][threadIdx.x] + red[3][threadIdx.x];
}

// ---------------- Parallel capacity scan (order-exact); also emits cnt ----------------
__global__ __launch_bounds__(256) void pos_k(const int* __restrict__ topi,
                                             const float* __restrict__ topw,
                                             int* __restrict__ slot,
                                             int* __restrict__ keep,
                                             int* __restrict__ s2t,
                                             float* __restrict__ s2w,
                                             float* __restrict__ cnt) {
  __shared__ int fi[8192];
  __shared__ int hist[256][16];
  __shared__ int total[16];
  const int t = threadIdx.x;
  for (int i = t; i < 8192; i += 256) fi[i] = topi[i];
#pragma unroll
  for (int e = 0; e < 16; ++e) hist[t][e] = 0;
  __syncthreads();
  const int base = t * 32;
#pragma unroll 8
  for (int i = 0; i < 32; ++i) hist[t][fi[base + i]]++;
  __syncthreads();
  if (t < 16) {
    int run = 0;
    for (int c = 0; c < 256; ++c) { const int v = hist[c][t]; hist[c][t] = run; run += v; }
    total[t] = run;
    cnt[t] = (float)run;
  }
  __syncthreads();
  int run[16];
#pragma unroll
  for (int e = 0; e < 16; ++e) run[e] = hist[t][e];
  for (int i = 0; i < 32; ++i) {
    const int idx = base + i;
    const int e = fi[idx];
    const int p = run[e]++;
    if (p < 640) {
      slot[idx] = p; keep[idx] = 1;
      s2t[e * 640 + p] = idx >> 1;
      s2w[e * 640 + p] = topw[idx];
    } else {
      slot[idx] = 639; keep[idx] = 0;
    }
  }
  __syncthreads();
  for (int pos = t; pos < 16 * 640; pos += 256) {
    const int e = pos / 640, c = pos - e * 640;
    if (c >= total[e]) s2t[pos] = -1;
  }
}

__global__ __launch_bounds__(128) void scatter_b_k(const unsigned short* __restrict__ xnb,
                                                   const int* __restrict__ topi,
                                                   const int* __restrict__ slot,
                                                   const int* __restrict__ keep,
                                                   unsigned short* __restrict__ buf) {
  const int i = blockIdx.x;
  if (!keep[i]) return;
  const int n = i >> 1;
  const size_t dst = ((size_t)topi[i] * 640 + slot[i]) * 1024;
  ((uint4*)(buf + dst))[threadIdx.x] = ((const uint4*)(xnb + (size_t)n * 1024))[threadIdx.x];
}

__global__ void aux_k(const float* __restrict__ cnt, const float* __restrict__ psum,
                      float* __restrict__ out) {
  if (threadIdx.x == 0) {
    float s = 0.f;
    for (int e = 0; e < 16; ++e)
      s += (cnt[e] * (1.f / 4096.f)) * (psum[e] * (1.f / 4096.f));
    out[0] = 16.f * s;
  }
}

// ---------------- tou softmax (fp32 in -> bf16 probs) + gate ----------------
__global__ __launch_bounds__(256) void softmax512_k(const float* __restrict__ sc,
                                                    unsigned short* __restrict__ out) {
  const long n = blockIdx.x;
  const float2* row = (const float2*)(sc + n * 512);
  const int t = threadIdx.x;
  float2 v = row[t];
  float mx = fmaxf(v.x, v.y);
#pragma unroll
  for (int o = 32; o > 0; o >>= 1) mx = fmaxf(mx, __shfl_down(mx, o));
  __shared__ float red[4];
  __shared__ float bm, bz;
  if ((t & 63) == 0) red[t >> 6] = mx;
  __syncthreads();
  if (t == 0) bm = fmaxf(fmaxf(red[0], red[1]), fmaxf(red[2], red[3]));
  __syncthreads();
  const float M = bm;
  const float e0 = expf(v.x - M), e1 = expf(v.y - M);
  float s = e0 + e1;
#pragma unroll
  for (int o = 32; o > 0; o >>= 1) s += __shfl_down(s, o);
  if ((t & 63) == 0) red[t >> 6] = s;
  __syncthreads();
  if (t == 0) bz = 1.f / (red[0] + red[1] + red[2] + red[3]);
  __syncthreads();
  ushort2 u; u.x = f2bf(e0 * bz); u.y = f2bf(e1 * bz);
  *(ushort2*)(out + n * 512 + t * 2) = u;
}

__global__ __launch_bounds__(256) void gate_k(const float* __restrict__ xn,
                                              const float* __restrict__ gw,
                                              const float* __restrict__ gb,
                                              float* __restrict__ gate) {
  const long n = blockIdx.x;
  const int t = threadIdx.x;
  const float4 v = ((const float4*)(xn + n * 1024))[t];
  const float4 g = ((const float4*)gw)[t];
  float s = v.x * g.x + v.y * g.y + v.z * g.z + v.w * g.w;
#pragma unroll
  for (int o = 32; o > 0; o >>= 1) s += __shfl_down(s, o);
  __shared__ float red[4];
  if ((t & 63) == 0) red[t >> 6] = s;
  __syncthreads();
  if (t == 0) {
    const float tot = red[0] + red[1] + red[2] + red[3] + gb[0];
    gate[n] = 1.f / (1.f + expf(-tot));
  }
}

extern "C" void kernel_launch(void* const* d_in, const int* in_sizes, int n_in,
                              void* d_out, int out_size, void* d_ws, size_t ws_size,
                              hipStream_t stream) {
  (void)in_sizes; (void)n_in; (void)out_size; (void)ws_size;
  const float* x    = (const float*)d_in[0];
  const float* prim = (const float*)d_in[1];
  const float* n1w  = (const float*)d_in[2];
  const float* qkvw = (const float*)d_in[3];
  const float* aow  = (const float*)d_in[4];
  const float* n2w  = (const float*)d_in[5];
  const float* rw   = (const float*)d_in[6];
  const float* w1   = (const float*)d_in[7];
  const float* w2   = (const float*)d_in[8];
  const float* n3w  = (const float*)d_in[9];
  const float* tqw  = (const float*)d_in[10];
  const float* tkw  = (const float*)d_in[11];
  const float* tvw  = (const float*)d_in[12];
  const float* tow  = (const float*)d_in[13];
  const float* tgw  = (const float*)d_in[14];
  const float* tgb  = (const float*)d_in[15];

  float* xbuf = (float*)d_out;
  float* aux  = xbuf + 4194304;

  char* W = (char*)d_ws;
  float* xn            = (float*)W;                           // 16 MB
  unsigned short* xnb  = (unsigned short*)(W + (16u << 20));  // 8 MB (hi)
  unsigned short* xnl  = (unsigned short*)(W + (24u << 20));  // 8 MB (lo)
  char* P = W + (32u << 20);

  // phase A
  unsigned short* qh   = (unsigned short*)(P + (48u << 20));
  unsigned short* ql   = (unsigned short*)(P + (56u << 20));
  unsigned short* kh   = (unsigned short*)(P + (64u << 20));
  unsigned short* kl   = (unsigned short*)(P + (72u << 20));
  unsigned short* vh   = (unsigned short*)(P + (80u << 20));
  unsigned short* vl   = (unsigned short*)(P + (88u << 20));
  unsigned short* axh  = (unsigned short*)(P + (112u << 20));
  unsigned short* axl  = (unsigned short*)(P + (120u << 20));
  unsigned short* qwh  = (unsigned short*)(P + (128u << 20));
  unsigned short* qwl  = (unsigned short*)(P + (134u << 20));
  unsigned short* aoh  = (unsigned short*)(P + (140u << 20));
  unsigned short* aol  = (unsigned short*)(P + (142u << 20));
  // phase B (aliases phase A)
  int*   topi = (int*)P;
  float* topw = (float*)(P + 65536);
  int*   slot = (int*)(P + 131072);
  int*   keep = (int*)(P + 196608);
  float* cnt  = (float*)(P + 262144);
  float* psum = (float*)(P + 262144 + 4096);
  int*   s2t  = (int*)(P + 327680);
  float* s2w  = (float*)(P + 393216);
  float* probs = (float*)(P + 458752);                        // 256 KB
  unsigned short* bufb = (unsigned short*)(P + (1u << 20));   // 21 MB
  unsigned short* hb   = (unsigned short*)(P + (22u << 20));  // 42 MB
  unsigned short* Wt   = (unsigned short*)(P + (64u << 20));  // 67 MB
  // phase C (aliases again)
  unsigned short* tqb  = (unsigned short*)P;
  unsigned short* tkb  = (unsigned short*)(P + (2u << 20));
  unsigned short* tvtb = (unsigned short*)(P + (3u << 20));
  float*          tsc  = (float*)(P + (4u << 20));
  unsigned short* tpb  = (unsigned short*)(P + (12u << 20));
  unsigned short* tavb = (unsigned short*)(P + (16u << 20));
  float*          gate = (float*)(P + (18u << 20));
  unsigned short* tqwb = (unsigned short*)(P + (19u << 20));
  unsigned short* tkwb = (unsigned short*)(P + (20u << 20));
  unsigned short* tvwb = (unsigned short*)(P + (21u << 20));
  unsigned short* towb = (unsigned short*)(P + (22u << 20));
  unsigned short* primb= (unsigned short*)(P + (23u << 20));

  // ---- phase A: x += rope_attention(rmsnorm(x)) ----
  rmsnorm_k<0, 1><<<4096, 256, 0, stream>>>(x, n1w, nullptr, xnb, xnl);
  split2_k<<<4096, 256, 0, stream>>>(qkvw, qwh, qwl, aow, aoh, aol);
  bgemm_s<3><<<dim3(24, 32, 1), 256, 0, stream>>>(xnb, xnl, qwh, qwl, nullptr,
      4096, 3072, 1024, nullptr, qh, ql, kh, kl, vh, vl);
  flash_k<<<dim3(32, 32), 256, 0, stream>>>(qh, ql, kh, kl, vh, vl, axh, axl);
  bgemm_s<2><<<dim3(8, 32, 1), 256, 0, stream>>>(axh, axl, aoh, aol, xbuf,
      4096, 1024, 1024, x, nullptr, nullptr, nullptr, nullptr, nullptr, nullptr);

  // ---- phase B: MoE ----
  rmsnorm_k<1, 0><<<4096, 256, 0, stream>>>(xbuf, n2w, xn, xnb, nullptr);
  router_k<<<4096, 256, 0, stream>>>(xn, rw, topi, topw, probs);
  psum_k<<<1, 256, 0, stream>>>(probs, psum);
  pos_k<<<1, 256, 0, stream>>>(topi, topw, slot, keep, s2t, s2w, cnt);
  scatter_b_k<<<8192, 128, 0, stream>>>(xnb, topi, slot, keep, bufb);
  cvt_t_k<<<dim3(64, 32, 16), 256, 0, stream>>>(w1, Wt, 1024, 2048);
  bgemm<3><<<dim3(16, 5, 16), 256, 0, stream>>>(bufb, Wt, hb, 640, 2048, 1024,
      (long)640 * 1024, (long)2048 * 1024, (long)640 * 2048, 1.f, nullptr, nullptr, nullptr);
  cvt_t_k<<<dim3(32, 64, 16), 256, 0, stream>>>(w2, Wt, 2048, 1024);
  bgemm<5><<<dim3(8, 5, 16), 256, 0, stream>>>(hb, Wt, xbuf, 640, 1024, 2048,
      (long)640 * 2048, (long)1024 * 2048, 0, 1.f, nullptr, s2t, s2w);
  aux_k<<<1, 64, 0, stream>>>(cnt, psum, aux);

  // ---- phase C: tou cross-attn ----
  rmsnorm_k<1, 0><<<4096, 256, 0, stream>>>(xbuf, n3w, xn, xnb, nullptr);
  cvt5_k<<<768, 256, 0, stream>>>(tqw, tqwb, tkw, tkwb, tvw, tvwb, tow, towb, prim, primb);
  bgemm<2><<<dim3(2, 32, 1), 256, 0, stream>>>(xnb, tqwb, tqb, 4096, 256, 1024, 0, 0, 0, 1.f, nullptr, nullptr, nullptr);
  bgemm<2><<<dim3(2, 4, 1), 256, 0, stream>>>(primb, tkwb, tkb, 512, 256, 256, 0, 0, 0, 1.f, nullptr, nullptr, nullptr);
  bgemm<2><<<dim3(4, 2, 1), 256, 0, stream>>>(tvwb, primb, tvtb, 256, 512, 256, 0, 0, 0, 1.f, nullptr, nullptr, nullptr);
  bgemm<0><<<dim3(4, 32, 1), 256, 0, stream>>>(tqb, tkb, tsc, 4096, 512, 256, 0, 0, 0, 0.0625f, nullptr, nullptr, nullptr);
  softmax512_k<<<4096, 256, 0, stream>>>(tsc, tpb);
  bgemm<2><<<dim3(2, 32, 1), 256, 0, stream>>>(tpb, tvtb, tavb, 4096, 256, 512, 0, 0, 0, 1.f, nullptr, nullptr, nullptr);
  gate_k<<<4096, 256, 0, stream>>>(xn, tgw, tgb, gate);
  bgemm<4><<<dim3(8, 32, 1), 256, 0, stream>>>(tavb, towb, xbuf, 4096, 1024, 256, 0, 0, 0, 1.f, gate, nullptr, nullptr);
}

// Round 4
// 962.463 us; speedup vs baseline: 1.2074x; 1.1314x over previous
//
#include <hip/hip_runtime.h>
#include <math.h>

// B=2 T=2048 D=1024 H=16 DH=64 E=16 K=2 F=2048 CAP=640 DP=256 NPRIM=512
typedef short bf16x8 __attribute__((ext_vector_type(8)));
typedef float f32x4 __attribute__((ext_vector_type(4)));

__device__ __forceinline__ unsigned short f2bf(float f) {
  union { float f; unsigned u; } v; v.f = f;
  return (unsigned short)((v.u + 0x7fff + ((v.u >> 16) & 1)) >> 16);
}
__device__ __forceinline__ float bf2f(unsigned short h) {
  union { unsigned u; float f; } v; v.u = ((unsigned)h) << 16;
  return v.f;
}

// Direct global->LDS DMA, 16B per lane. LDS dest is wave-uniform base + lane*16.
__device__ __forceinline__ void gld16(const unsigned short* g, unsigned short* l) {
  __builtin_amdgcn_global_load_lds((const __attribute__((address_space(1))) void*)g,
                                   (__attribute__((address_space(3))) void*)l, 16, 0, 0);
}

// ---------------- RMSNorm: optional fp32 out, bf16-hi out, optional bf16-lo out ----------------
template <int WF32, int WLO>
__global__ __launch_bounds__(256) void rmsnorm_k(const float* __restrict__ x,
                                                 const float* __restrict__ w,
                                                 float* __restrict__ y,
                                                 unsigned short* __restrict__ yb,
                                                 unsigned short* __restrict__ yl) {
  const long n = blockIdx.x;
  const int t = threadIdx.x;
  const float4 v = ((const float4*)(x + n * 1024))[t];
  float ss = v.x * v.x + v.y * v.y + v.z * v.z + v.w * v.w;
#pragma unroll
  for (int o = 32; o > 0; o >>= 1) ss += __shfl_down(ss, o);
  __shared__ float red[4];
  __shared__ float sc;
  if ((t & 63) == 0) red[t >> 6] = ss;
  __syncthreads();
  if (t == 0) sc = rsqrtf((red[0] + red[1] + red[2] + red[3]) * (1.0f / 1024.0f) + 1e-6f);
  __syncthreads();
  const float s = sc;
  const float4 wv = ((const float4*)w)[t];
  float4 o;
  o.x = v.x * s * wv.x; o.y = v.y * s * wv.y; o.z = v.z * s * wv.z; o.w = v.w * s * wv.w;
  if (WF32) ((float4*)(y + n * 1024))[t] = o;
  ushort4 u = make_ushort4(f2bf(o.x), f2bf(o.y), f2bf(o.z), f2bf(o.w));
  *(ushort4*)(yb + n * 1024 + t * 4) = u;
  if (WLO) {
    ushort4 l = make_ushort4(f2bf(o.x - bf2f(u.x)), f2bf(o.y - bf2f(u.y)),
                             f2bf(o.z - bf2f(u.z)), f2bf(o.w - bf2f(u.w)));
    *(ushort4*)(yl + n * 1024 + t * 4) = l;
  }
}

// ---------------- fused weight hi/lo splits: qkvw (786432 f4) + aow (262144 f4) ----------------
__global__ __launch_bounds__(256) void split2_k(const float* __restrict__ s0,
                                                unsigned short* __restrict__ h0,
                                                unsigned short* __restrict__ l0,
                                                const float* __restrict__ s1,
                                                unsigned short* __restrict__ h1,
                                                unsigned short* __restrict__ l1) {
  const int i = blockIdx.x * 256 + threadIdx.x;  // 4096*256 = 1048576 float4 groups
  const float* s; unsigned short* hp; unsigned short* lp; int off;
  if (i < 786432) { s = s0; hp = h0; lp = l0; off = i; }
  else            { s = s1; hp = h1; lp = l1; off = i - 786432; }
  const float4 v = ((const float4*)s)[off];
  ushort4 h = make_ushort4(f2bf(v.x), f2bf(v.y), f2bf(v.z), f2bf(v.w));
  ushort4 l = make_ushort4(f2bf(v.x - bf2f(h.x)), f2bf(v.y - bf2f(h.y)),
                           f2bf(v.z - bf2f(h.z)), f2bf(v.w - bf2f(h.w)));
  ((ushort4*)hp)[off] = h;
  ((ushort4*)lp)[off] = l;
}

// ---------------- fused phase-C weight conversions (5 regions, 1 launch) ----------------
__global__ __launch_bounds__(256) void cvt5_k(const float* __restrict__ s0, unsigned short* __restrict__ d0,
                                              const float* __restrict__ s1, unsigned short* __restrict__ d1,
                                              const float* __restrict__ s2, unsigned short* __restrict__ d2,
                                              const float* __restrict__ s3, unsigned short* __restrict__ d3,
                                              const float* __restrict__ s4, unsigned short* __restrict__ d4) {
  const int i = blockIdx.x * 256 + threadIdx.x;  // 768*256 = 196608 float4 groups total
  const float* s; unsigned short* d; int off;
  if (i < 65536)       { s = s0; d = d0; off = i; }
  else if (i < 81920)  { s = s1; d = d1; off = i - 65536; }
  else if (i < 98304)  { s = s2; d = d2; off = i - 81920; }
  else if (i < 163840) { s = s3; d = d3; off = i - 98304; }
  else                 { s = s4; d = d4; off = i - 163840; }
  const float4 v = ((const float4*)s)[off];
  ((ushort4*)d)[off] = make_ushort4(f2bf(v.x), f2bf(v.y), f2bf(v.z), f2bf(v.w));
}

// ---------------- transpose-convert: (R,C) fp32 -> (C,R) bf16, batched ----------------
__global__ __launch_bounds__(256) void cvt_t_k(const float* __restrict__ in,
                                               unsigned short* __restrict__ out,
                                               int R, int C) {
  in += (size_t)blockIdx.z * R * C;
  out += (size_t)blockIdx.z * R * C;
  const int r0 = blockIdx.y * 32, c0 = blockIdx.x * 32;
  __shared__ float T[32][33];
  const int tid = threadIdx.x;
  const int li = tid >> 3;
  const int lj = (tid & 7) << 2;
  const float4 v = *(const float4*)(in + (size_t)(r0 + li) * C + c0 + lj);
  T[li][lj + 0] = v.x; T[li][lj + 1] = v.y; T[li][lj + 2] = v.z; T[li][lj + 3] = v.w;
  __syncthreads();
  ushort4 u = make_ushort4(f2bf(T[lj + 0][li]), f2bf(T[lj + 1][li]),
                           f2bf(T[lj + 2][li]), f2bf(T[lj + 3][li]));
  *(ushort4*)(out + (size_t)(c0 + li) * R + r0 + lj) = u;
}

// ---------------- bf16 transpose: per z, (2048,64) -> (64,2048); z<32: pair0, else pair1 ----------------
__global__ __launch_bounds__(256) void cvt_tb_k(const unsigned short* __restrict__ in0,
                                                unsigned short* __restrict__ out0,
                                                const unsigned short* __restrict__ in1,
                                                unsigned short* __restrict__ out1) {
  const int zz = blockIdx.z;
  const unsigned short* in = (zz < 32 ? in0 : in1) + (size_t)(zz & 31) * 2048 * 64;
  unsigned short* out = (zz < 32 ? out0 : out1) + (size_t)(zz & 31) * 2048 * 64;
  const int r0 = blockIdx.y * 32, c0 = blockIdx.x * 32;
  __shared__ unsigned short T[32][36];
  const int tid = threadIdx.x;
  const int li = tid >> 3;
  const int lj = (tid & 7) << 2;
  const ushort4 v = *(const ushort4*)(in + (size_t)(r0 + li) * 64 + c0 + lj);
  T[li][lj + 0] = v.x; T[li][lj + 1] = v.y; T[li][lj + 2] = v.z; T[li][lj + 3] = v.w;
  __syncthreads();
  ushort4 u = make_ushort4(T[lj + 0][li], T[lj + 1][li], T[lj + 2][li], T[lj + 3][li]);
  *(ushort4*)(out + (size_t)(c0 + li) * 2048 + r0 + lj) = u;
}

// ---------------- bf16 MFMA GEMM: C(M,N) = alpha * A(M,K) x B(N,K)^T ----------------
// m97 structure: linear LDS + global_load_lds width-16 staging (no reg round-trip).
// MODE: 0=f32 store, 1=f32 +=, 2=bf16 store, 3=bf16 silu store,
//       4=f32 += rowscale[row]*v, 5=f32 atomicAdd to rowmap token (MoE un-scatter)
template <int MODE>
__global__ __launch_bounds__(256) void bgemm(const unsigned short* __restrict__ A,
                                             const unsigned short* __restrict__ B,
                                             void* __restrict__ Cv,
                                             int M, int N, int K,
                                             long sA, long sB, long sC, float alpha,
                                             const float* __restrict__ rowscale,
                                             const int* __restrict__ rowmap,
                                             const float* __restrict__ roww) {
  __shared__ __align__(16) unsigned short As[128 * 32];
  __shared__ __align__(16) unsigned short Bs[128 * 32];
  const int tid = threadIdx.x;
  const int z = blockIdx.z;
  const unsigned short* Ag = A + (size_t)z * sA;
  const unsigned short* Bg = B + (size_t)z * sB;
  const int m0 = blockIdx.y * 128, n0 = blockIdx.x * 128;
  const int lane = tid & 63;
  const int wid = tid >> 6;
  const int wm = (wid >> 1) * 64, wn = (wid & 1) * 64;
  const int fr = lane & 15, fq = lane >> 4;
  const int lr = tid >> 2, lk = (tid & 3) * 8;
  f32x4 acc[4][4] = {};
  const unsigned short* Ap0 = Ag + (size_t)(m0 + lr) * K + lk;
  const unsigned short* Ap1 = Ag + (size_t)(m0 + lr + 64) * K + lk;
  const unsigned short* Bp0 = Bg + (size_t)(n0 + lr) * K + lk;
  const unsigned short* Bp1 = Bg + (size_t)(n0 + lr + 64) * K + lk;
  unsigned short* Asw = As + wid * 512;  // wave-uniform LDS base (bytes: wid*1024)
  unsigned short* Bsw = Bs + wid * 512;
  gld16(Ap0, Asw); gld16(Ap1, Asw + 2048);
  gld16(Bp0, Bsw); gld16(Bp1, Bsw + 2048);
  for (int k0 = 0;;) {
    __syncthreads();  // drains vmcnt: staged tile visible to all waves
    bf16x8 af[4], bv[4];
#pragma unroll
    for (int i = 0; i < 4; ++i) af[i] = *(const bf16x8*)&As[(wm + i * 16 + fr) * 32 + fq * 8];
#pragma unroll
    for (int j = 0; j < 4; ++j) bv[j] = *(const bf16x8*)&Bs[(wn + j * 16 + fr) * 32 + fq * 8];
    __syncthreads();  // all frag reads done -> safe to overwrite tile
    k0 += 32;
    if (k0 < K) {     // next-tile DMA overlaps the MFMAs below
      gld16(Ap0 + k0, Asw); gld16(Ap1 + k0, Asw + 2048);
      gld16(Bp0 + k0, Bsw); gld16(Bp1 + k0, Bsw + 2048);
    }
#pragma unroll
    for (int i = 0; i < 4; ++i)
#pragma unroll
      for (int j = 0; j < 4; ++j)
        acc[i][j] = __builtin_amdgcn_mfma_f32_16x16x32_bf16(af[i], bv[j], acc[i][j], 0, 0, 0);
    if (k0 >= K) break;
  }
#pragma unroll
  for (int i = 0; i < 4; ++i) {
#pragma unroll
    for (int reg = 0; reg < 4; ++reg) {
      const int row = m0 + wm + i * 16 + fq * 4 + reg;
      float rs = 0.f, wgt = 0.f;
      int tok = -1;
      if (MODE == 4) rs = rowscale[row];
      if (MODE == 5) {
        tok = rowmap[z * M + row];
        if (tok >= 0) wgt = roww[z * M + row];
      }
#pragma unroll
      for (int j = 0; j < 4; ++j) {
        const int col = n0 + wn + j * 16 + fr;
        const float v = alpha * acc[i][j][reg];
        if (MODE == 0) {
          ((float*)Cv + (size_t)z * sC)[(size_t)row * N + col] = v;
        } else if (MODE == 1) {
          float* p = (float*)Cv + (size_t)z * sC + (size_t)row * N + col;
          *p += v;
        } else if (MODE == 2) {
          ((unsigned short*)Cv + (size_t)z * sC)[(size_t)row * N + col] = f2bf(v);
        } else if (MODE == 3) {
          const float sv = v / (1.f + __expf(-v));
          ((unsigned short*)Cv + (size_t)z * sC)[(size_t)row * N + col] = f2bf(sv);
        } else if (MODE == 4) {
          float* p = (float*)Cv + (size_t)row * N + col;
          *p += rs * v;
        } else if (MODE == 5) {
          if (tok >= 0) atomicAdd((float*)Cv + (size_t)tok * N + col, wgt * v);
        }
      }
    }
  }
}

// ---------------- Fused split-bf16 GEMM: C = (Ah+Al)(Bh+Bl)^T (3-term) ----------------
// MODE: 0 = f32 store, 1 = f32 +=, 2 = f32 store of res[row,col] + v (residual fuse),
//       3 = fused RoPE + hi/lo split QKV output to [bh][t][dh] (no C)
template <int MODE>
__global__ __launch_bounds__(256) void bgemm_s(const unsigned short* __restrict__ Ah,
                                               const unsigned short* __restrict__ Al,
                                               const unsigned short* __restrict__ Bh,
                                               const unsigned short* __restrict__ Bl,
                                               float* __restrict__ C,
                                               int M, int N, int K,
                                               const float* __restrict__ res,
                                               unsigned short* __restrict__ Qh,
                                               unsigned short* __restrict__ Ql,
                                               unsigned short* __restrict__ Kh,
                                               unsigned short* __restrict__ Kl,
                                               unsigned short* __restrict__ Vh,
                                               unsigned short* __restrict__ Vl) {
  __shared__ __align__(16) unsigned short Ash[128 * 32];
  __shared__ __align__(16) unsigned short Asl[128 * 32];
  __shared__ __align__(16) unsigned short Bsh[128 * 32];
  __shared__ __align__(16) unsigned short Bsl[128 * 32];
  const int tid = threadIdx.x;
  const int m0 = blockIdx.y * 128, n0 = blockIdx.x * 128;
  const int lane = tid & 63;
  const int wid = tid >> 6;
  const int wm = (wid >> 1) * 64, wn = (wid & 1) * 64;
  const int fr = lane & 15, fq = lane >> 4;
  const int lr = tid >> 2, lk = (tid & 3) * 8;
  f32x4 acc[4][4] = {};
  const size_t oA0 = (size_t)(m0 + lr) * K + lk, oA1 = (size_t)(m0 + lr + 64) * K + lk;
  const size_t oB0 = (size_t)(n0 + lr) * K + lk, oB1 = (size_t)(n0 + lr + 64) * K + lk;
  const int wb = wid * 512;
  gld16(Ah + oA0, Ash + wb); gld16(Ah + oA1, Ash + wb + 2048);
  gld16(Al + oA0, Asl + wb); gld16(Al + oA1, Asl + wb + 2048);
  gld16(Bh + oB0, Bsh + wb); gld16(Bh + oB1, Bsh + wb + 2048);
  gld16(Bl + oB0, Bsl + wb); gld16(Bl + oB1, Bsl + wb + 2048);
  for (int k0 = 0;;) {
    __syncthreads();
    bf16x8 afh[4], afl[4], bvh[4], bvl[4];
#pragma unroll
    for (int i = 0; i < 4; ++i) {
      afh[i] = *(const bf16x8*)&Ash[(wm + i * 16 + fr) * 32 + fq * 8];
      afl[i] = *(const bf16x8*)&Asl[(wm + i * 16 + fr) * 32 + fq * 8];
    }
#pragma unroll
    for (int j = 0; j < 4; ++j) {
      bvh[j] = *(const bf16x8*)&Bsh[(wn + j * 16 + fr) * 32 + fq * 8];
      bvl[j] = *(const bf16x8*)&Bsl[(wn + j * 16 + fr) * 32 + fq * 8];
    }
    __syncthreads();
    k0 += 32;
    if (k0 < K) {
      gld16(Ah + oA0 + k0, Ash + wb); gld16(Ah + oA1 + k0, Ash + wb + 2048);
      gld16(Al + oA0 + k0, Asl + wb); gld16(Al + oA1 + k0, Asl + wb + 2048);
      gld16(Bh + oB0 + k0, Bsh + wb); gld16(Bh + oB1 + k0, Bsh + wb + 2048);
      gld16(Bl + oB0 + k0, Bsl + wb); gld16(Bl + oB1 + k0, Bsl + wb + 2048);
    }
#pragma unroll
    for (int j = 0; j < 4; ++j) {
#pragma unroll
      for (int i = 0; i < 4; ++i) {
        acc[i][j] = __builtin_amdgcn_mfma_f32_16x16x32_bf16(afl[i], bvh[j], acc[i][j], 0, 0, 0);
        acc[i][j] = __builtin_amdgcn_mfma_f32_16x16x32_bf16(afh[i], bvl[j], acc[i][j], 0, 0, 0);
        acc[i][j] = __builtin_amdgcn_mfma_f32_16x16x32_bf16(afh[i], bvh[j], acc[i][j], 0, 0, 0);
      }
    }
    if (k0 >= K) break;
  }
  if (MODE == 3) {
    // Fused RoPE + hi/lo split. Each (i,reg) holds cols d = fr, fr+16, fr+32, fr+48 of
    // ONE head-band (n0+wn is 64-aligned; 1024%64==0 so band never crosses q/k/v).
    const int band = n0 + wn;
    const int which = band >> 10;           // 0=q 1=k 2=v
    const int h = (band & 1023) >> 6;
    unsigned short* Hp = (which == 0) ? Qh : ((which == 1) ? Kh : Vh);
    unsigned short* Lp = (which == 0) ? Ql : ((which == 1) ? Kl : Vl);
    const float l2t = 13.287712379549449f;  // log2(10000)
    const float inv0 = exp2f(-l2t * (float)fr * (1.0f / 32.0f));
    const float inv1 = exp2f(-l2t * (float)(fr + 16) * (1.0f / 32.0f));
#pragma unroll
    for (int i = 0; i < 4; ++i) {
#pragma unroll
      for (int reg = 0; reg < 4; ++reg) {
        const int row = m0 + wm + i * 16 + fq * 4 + reg;
        const int b = row >> 11, t = row & 2047;
        float o0 = acc[i][0][reg], o1 = acc[i][1][reg];
        float o2 = acc[i][2][reg], o3 = acc[i][3][reg];
        if (which != 2) {
          const float a0 = (float)t * inv0, a1 = (float)t * inv1;
          const float c0 = cosf(a0), sn0 = sinf(a0);
          const float c1 = cosf(a1), sn1 = sinf(a1);
          const float v0 = o0, v1 = o1, v2 = o2, v3 = o3;
          o0 = v0 * c0 - v2 * sn0;   // d = fr        (<32): pair +32 negated
          o1 = v1 * c1 - v3 * sn1;   // d = fr+16
          o2 = v2 * c0 + v0 * sn0;   // d = fr+32     (>=32): pair -32
          o3 = v3 * c1 + v1 * sn1;   // d = fr+48
        }
        const long bo = ((long)((b << 4) + h) * 2048 + t) * 64 + fr;
        const unsigned short h0 = f2bf(o0), h1 = f2bf(o1);
        const unsigned short h2 = f2bf(o2), h3 = f2bf(o3);
        Hp[bo] = h0; Hp[bo + 16] = h1; Hp[bo + 32] = h2; Hp[bo + 48] = h3;
        Lp[bo]      = f2bf(o0 - bf2f(h0));
        Lp[bo + 16] = f2bf(o1 - bf2f(h1));
        Lp[bo + 32] = f2bf(o2 - bf2f(h2));
        Lp[bo + 48] = f2bf(o3 - bf2f(h3));
      }
    }
  } else {
#pragma unroll
    for (int i = 0; i < 4; ++i) {
#pragma unroll
      for (int reg = 0; reg < 4; ++reg) {
        const int row = m0 + wm + i * 16 + fq * 4 + reg;
#pragma unroll
        for (int j = 0; j < 4; ++j) {
          const int col = n0 + wn + j * 16 + fr;
          float* p = C + (size_t)row * N + col;
          if (MODE == 0) *p = acc[i][j][reg];
          else if (MODE == 1) *p += acc[i][j][reg];
          else *p = res[(size_t)row * N + col] + acc[i][j][reg];
        }
      }
    }
  }
}

// ---------------- Split-bf16 MFMA flash attention, v3 ----------------
// K and V^T both staged by global_load_lds with pre-swizzled SOURCE (linear LDS dest).
// V^T precomputed in global by cvt_tb_k -> zero in-loop transpose VALU/LDS-writes.
// Single-buffered, 2 barriers/iter: K-DMA(kb+1) issued after barrier A (overlaps PV),
// V-DMA(kb+1) issued after barrier B (overlaps next QK/softmax).
__global__ __launch_bounds__(256) void flash_k(const unsigned short* __restrict__ Qhg,
                                               const unsigned short* __restrict__ Qlg,
                                               const unsigned short* __restrict__ Khg,
                                               const unsigned short* __restrict__ Klg,
                                               const unsigned short* __restrict__ Vthg,
                                               const unsigned short* __restrict__ Vtlg,
                                               unsigned short* __restrict__ axh,
                                               unsigned short* __restrict__ axl) {
  const int qb = (int)gridDim.x - 1 - (int)blockIdx.x;  // heavy tiles first
  const int bh = blockIdx.y;
  const int b = bh >> 4, h = bh & 15;
  const int q0 = qb << 6;
  __shared__ __align__(16) unsigned short Ksh[64 * 64];
  __shared__ __align__(16) unsigned short Ksl[64 * 64];
  __shared__ __align__(16) unsigned short Vth[64 * 64];  // V^T: row d, col t (swizzled)
  __shared__ __align__(16) unsigned short Vtl[64 * 64];
  __shared__ __align__(16) unsigned short Psh[4 * 16 * 64];
  __shared__ __align__(16) unsigned short Psl[4 * 16 * 64];
  const int tid = threadIdx.x;
  const int w = tid >> 6;
  const int lane = tid & 63;
  const int fr = lane & 15, fq = lane >> 4;
  const long base_q = ((long)bh * 2048 + q0) * 64;
  const long kv_base = (long)bh * 2048 * 64;  // K: [bh][t][64]; V^T: [bh][d][2048]
  // Q in registers (per-wave static fragments)
  bf16x8 qh_r[2], ql_r[2];
#pragma unroll
  for (int kc = 0; kc < 2; ++kc) {
    qh_r[kc] = *(const bf16x8*)(Qhg + base_q + (w * 16 + fr) * 64 + kc * 32 + fq * 8);
    ql_r[kc] = *(const bf16x8*)(Qlg + base_q + (w * 16 + fr) * 64 + kc * 32 + fq * 8);
  }
  f32x4 o_acc[4] = {};
  float m_st[4], l_st[4];
#pragma unroll
  for (int i = 0; i < 4; ++i) { m_st[i] = -3.0e38f; l_st[i] = 0.f; }

  // ---- prologue: stage K(0), V^T(0) ----
  {
#pragma unroll
    for (int rep = 0; rep < 2; ++rep) {
      const int f = tid + rep * 256;
      const int r = f >> 3, c = f & 7;
      const long srcK = kv_base + r * 64 + ((c ^ (r & 7)) * 8);
      gld16(Khg + srcK, Ksh + f * 8);
      gld16(Klg + srcK, Ksl + f * 8);
      const long srcV = kv_base + (long)r * 2048 + ((c ^ (r & 7)) * 8);  // d=r, t0=0
      gld16(Vthg + srcV, Vth + f * 8);
      gld16(Vtlg + srcV, Vtl + f * 8);
    }
    __syncthreads();  // drains all DMA
  }

  for (int kb = 0;; ++kb) {
    const bool more = (kb < qb);
    // ---- 1. QK^T (reads Ksh/Ksl + Q regs) ----
    f32x4 sfr[4] = {};
    __builtin_amdgcn_s_setprio(1);
#pragma unroll
    for (int kc = 0; kc < 2; ++kc) {
#pragma unroll
      for (int j = 0; j < 4; ++j) {
        const int co = (j * 16 + fr) * 64 + ((kc * 32 + fq * 8) ^ ((fr & 7) << 3));
        const bf16x8 kh_ = *(const bf16x8*)&Ksh[co];
        const bf16x8 kl_ = *(const bf16x8*)&Ksl[co];
        sfr[j] = __builtin_amdgcn_mfma_f32_16x16x32_bf16(ql_r[kc], kh_, sfr[j], 0, 0, 0);
        sfr[j] = __builtin_amdgcn_mfma_f32_16x16x32_bf16(qh_r[kc], kl_, sfr[j], 0, 0, 0);
        sfr[j] = __builtin_amdgcn_mfma_f32_16x16x32_bf16(qh_r[kc], kh_, sfr[j], 0, 0, 0);
      }
    }
    __builtin_amdgcn_s_setprio(0);
    // ---- 2. online softmax + P -> LDS (wave-local region) ----
    const bool diag = (kb == qb);
    float p[4][4];
    float alpha[4];
#pragma unroll
    for (int reg = 0; reg < 4; ++reg) {
      const int qloc = w * 16 + fq * 4 + reg;
      float v[4];
#pragma unroll
      for (int j = 0; j < 4; ++j) {
        float s = sfr[j][reg] * 0.125f;
        if (diag && (j * 16 + fr) > qloc) s = -1.0e30f;
        v[j] = s;
      }
      float mt = fmaxf(fmaxf(v[0], v[1]), fmaxf(v[2], v[3]));
#pragma unroll
      for (int off = 1; off < 16; off <<= 1) mt = fmaxf(mt, __shfl_xor(mt, off));
      const float mn = fmaxf(m_st[reg], mt);
      alpha[reg] = __expf(m_st[reg] - mn);
      m_st[reg] = mn;
      float ps = 0.f;
#pragma unroll
      for (int j = 0; j < 4; ++j) { p[j][reg] = __expf(v[j] - mn); ps += p[j][reg]; }
#pragma unroll
      for (int off = 1; off < 16; off <<= 1) ps += __shfl_xor(ps, off);
      l_st[reg] = l_st[reg] * alpha[reg] + ps;
    }
#pragma unroll
    for (int reg = 0; reg < 4; ++reg) {
      const int qp = fq * 4 + reg;
#pragma unroll
      for (int j = 0; j < 4; ++j) {
        const float pv = p[j][reg];
        const unsigned short ph = f2bf(pv);
        const unsigned short pl = f2bf(pv - bf2f(ph));
        const int sa = w * 1024 + qp * 64 + ((j * 16 + fr) ^ ((qp & 7) << 3));
        Psh[sa] = ph;
        Psl[sa] = pl;
      }
    }
#pragma unroll
    for (int j = 0; j < 4; ++j)
#pragma unroll
      for (int reg = 0; reg < 4; ++reg) o_acc[j][reg] *= alpha[reg];
    // ---- 3. barrier A: K(kb) reads + P writes done; drains V-DMA(kb) ----
    __syncthreads();
    // ---- 4. issue K(kb+1) DMA (overlaps PV; drained at barrier B) ----
    if (more) {
      const long bk = kv_base + (long)((kb + 1) << 6) * 64;
#pragma unroll
      for (int rep = 0; rep < 2; ++rep) {
        const int f = tid + rep * 256;
        const int r = f >> 3, c = f & 7;
        const long src = bk + r * 64 + ((c ^ (r & 7)) * 8);
        gld16(Khg + src, Ksh + f * 8);
        gld16(Klg + src, Ksl + f * 8);
      }
    }
    // ---- 5. PV (reads Vth/Vtl + Psh/Psl) ----
    __builtin_amdgcn_s_setprio(1);
#pragma unroll
    for (int kc = 0; kc < 2; ++kc) {
      const int po = w * 1024 + fr * 64 + ((kc * 32 + fq * 8) ^ ((fr & 7) << 3));
      const bf16x8 ph_ = *(const bf16x8*)&Psh[po];
      const bf16x8 pl_ = *(const bf16x8*)&Psl[po];
#pragma unroll
      for (int j = 0; j < 4; ++j) {
        const int co = (j * 16 + fr) * 64 + ((kc * 32 + fq * 8) ^ ((fr & 7) << 3));
        const bf16x8 vh_ = *(const bf16x8*)&Vth[co];
        const bf16x8 vl_ = *(const bf16x8*)&Vtl[co];
        o_acc[j] = __builtin_amdgcn_mfma_f32_16x16x32_bf16(pl_, vh_, o_acc[j], 0, 0, 0);
        o_acc[j] = __builtin_amdgcn_mfma_f32_16x16x32_bf16(ph_, vl_, o_acc[j], 0, 0, 0);
        o_acc[j] = __builtin_amdgcn_mfma_f32_16x16x32_bf16(ph_, vh_, o_acc[j], 0, 0, 0);
      }
    }
    __builtin_amdgcn_s_setprio(0);
    if (!more) break;
    // ---- 6. barrier B: V(kb)/P(kb) reads done; drains K-DMA(kb+1) ----
    __syncthreads();
    // ---- 7. issue V^T(kb+1) DMA (overlaps next QK+softmax; drained at barrier A) ----
    {
      const int t0 = (kb + 1) << 6;
#pragma unroll
      for (int rep = 0; rep < 2; ++rep) {
        const int f = tid + rep * 256;
        const int d = f >> 3, c = f & 7;
        const long src = kv_base + (long)d * 2048 + t0 + ((c ^ (d & 7)) * 8);
        gld16(Vthg + src, Vth + f * 8);
        gld16(Vtlg + src, Vtl + f * 8);
      }
    }
  }
#pragma unroll
  for (int reg = 0; reg < 4; ++reg) {
    const long tok = (long)b * 2048 + q0 + w * 16 + fq * 4 + reg;
    const float il = 1.f / l_st[reg];
#pragma unroll
    for (int j = 0; j < 4; ++j) {
      const float v = o_acc[j][reg] * il;
      const unsigned short hi = f2bf(v);
      const unsigned short lo = f2bf(v - bf2f(hi));
      const long off = tok * 1024 + h * 64 + j * 16 + fr;
      axh[off] = hi;
      axl[off] = lo;
    }
  }
}

// ---------------- Router: coalesced dot, no atomics, probs to workspace ----------------
__global__ __launch_bounds__(256) void router_k(const float* __restrict__ xn,
                                                const float* __restrict__ rw,
                                                int* __restrict__ topi,
                                                float* __restrict__ topw,
                                                float* __restrict__ probs) {
  const int n = blockIdx.x;
  const int t = threadIdx.x;
  const float4 xv = ((const float4*)(xn + (size_t)n * 1024))[t];
  float acc[16];
#pragma unroll
  for (int e = 0; e < 16; ++e) {
    const float4 wv = ((const float4*)(rw + (size_t)e * 1024))[t];
    acc[e] = xv.x * wv.x + xv.y * wv.y + xv.z * wv.z + xv.w * wv.w;
  }
#pragma unroll
  for (int e = 0; e < 16; ++e)
#pragma unroll
    for (int o = 32; o > 0; o >>= 1) acc[e] += __shfl_down(acc[e], o);
  __shared__ float red[4][16];
  if ((t & 63) == 0) {
#pragma unroll
    for (int e = 0; e < 16; ++e) red[t >> 6][e] = acc[e];
  }
  __syncthreads();
  if (t == 0) {
    float logits[16];
#pragma unroll
    for (int e = 0; e < 16; ++e)
      logits[e] = red[0][e] + red[1][e] + red[2][e] + red[3][e];
    float mx = logits[0];
#pragma unroll
    for (int e = 1; e < 16; ++e) mx = fmaxf(mx, logits[e]);
    float p[16];
    float Z = 0.f;
#pragma unroll
    for (int e = 0; e < 16; ++e) { p[e] = expf(logits[e] - mx); Z += p[e]; }
    const float iz = 1.f / Z;
#pragma unroll
    for (int e = 0; e < 16; ++e) p[e] *= iz;
    int i1 = 0;
#pragma unroll
    for (int e = 1; e < 16; ++e) if (p[e] > p[i1]) i1 = e;
    int i2 = (i1 == 0) ? 1 : 0;
#pragma unroll
    for (int e = 0; e < 16; ++e) if (e != i1 && p[e] > p[i2]) i2 = e;
    const float sw = p[i1] + p[i2];
    topi[2 * n] = i1; topi[2 * n + 1] = i2;
    topw[2 * n] = p[i1] / sw; topw[2 * n + 1] = p[i2] / sw;
    float* pr = probs + (size_t)n * 16;
#pragma unroll
    for (int e = 0; e < 16; ++e) pr[e] = p[e];
  }
}

// ---------------- psum reduction (single block) ----------------
__global__ __launch_bounds__(256) void psum_k(const float* __restrict__ probs,
                                              float* __restrict__ psum) {
  float acc[16] = {};
  for (int n = threadIdx.x; n < 4096; n += 256) {
    const float4* pr = (const float4*)(probs + (size_t)n * 16);
#pragma unroll
    for (int q = 0; q < 4; ++q) {
      const float4 v = pr[q];
      acc[q * 4 + 0] += v.x; acc[q * 4 + 1] += v.y;
      acc[q * 4 + 2] += v.z; acc[q * 4 + 3] += v.w;
    }
  }
#pragma unroll
  for (int e = 0; e < 16; ++e)
#pragma unroll
    for (int o = 32; o > 0; o >>= 1) acc[e] += __shfl_down(acc[e], o);
  __shared__ float red[4][16];
  if ((threadIdx.x & 63) == 0) {
#pragma unroll
    for (int e = 0; e < 16; ++e) red[threadIdx.x >> 6][e] = acc[e];
  }
  __syncthreads();
  if (threadIdx.x < 16)
    psum[threadIdx.x] = red[0][threadIdx.x] + red[1][threadIdx.x] +
                        red[2][threadIdx.x] + red[3][threadIdx.x];
}

// ---------------- Parallel capacity scan (order-exact); also emits cnt ----------------
__global__ __launch_bounds__(256) void pos_k(const int* __restrict__ topi,
                                             const float* __restrict__ topw,
                                             int* __restrict__ slot,
                                             int* __restrict__ keep,
                                             int* __restrict__ s2t,
                                             float* __restrict__ s2w,
                                             float* __restrict__ cnt) {
  __shared__ int fi[8192];
  __shared__ int hist[256][16];
  __shared__ int total[16];
  const int t = threadIdx.x;
  for (int i = t; i < 8192; i += 256) fi[i] = topi[i];
#pragma unroll
  for (int e = 0; e < 16; ++e) hist[t][e] = 0;
  __syncthreads();
  const int base = t * 32;
#pragma unroll 8
  for (int i = 0; i < 32; ++i) hist[t][fi[base + i]]++;
  __syncthreads();
  if (t < 16) {
    int run = 0;
    for (int c = 0; c < 256; ++c) { const int v = hist[c][t]; hist[c][t] = run; run += v; }
    total[t] = run;
    cnt[t] = (float)run;
  }
  __syncthreads();
  int run[16];
#pragma unroll
  for (int e = 0; e < 16; ++e) run[e] = hist[t][e];
  for (int i = 0; i < 32; ++i) {
    const int idx = base + i;
    const int e = fi[idx];
    const int p = run[e]++;
    if (p < 640) {
      slot[idx] = p; keep[idx] = 1;
      s2t[e * 640 + p] = idx >> 1;
      s2w[e * 640 + p] = topw[idx];
    } else {
      slot[idx] = 639; keep[idx] = 0;
    }
  }
  __syncthreads();
  for (int pos = t; pos < 16 * 640; pos += 256) {
    const int e = pos / 640, c = pos - e * 640;
    if (c >= total[e]) s2t[pos] = -1;
  }
}

__global__ __launch_bounds__(128) void scatter_b_k(const unsigned short* __restrict__ xnb,
                                                   const int* __restrict__ topi,
                                                   const int* __restrict__ slot,
                                                   const int* __restrict__ keep,
                                                   unsigned short* __restrict__ buf) {
  const int i = blockIdx.x;
  if (!keep[i]) return;
  const int n = i >> 1;
  const size_t dst = ((size_t)topi[i] * 640 + slot[i]) * 1024;
  ((uint4*)(buf + dst))[threadIdx.x] = ((const uint4*)(xnb + (size_t)n * 1024))[threadIdx.x];
}

__global__ void aux_k(const float* __restrict__ cnt, const float* __restrict__ psum,
                      float* __restrict__ out) {
  if (threadIdx.x == 0) {
    float s = 0.f;
    for (int e = 0; e < 16; ++e)
      s += (cnt[e] * (1.f / 4096.f)) * (psum[e] * (1.f / 4096.f));
    out[0] = 16.f * s;
  }
}

// ---------------- tou softmax (fp32 in -> bf16 probs) + gate ----------------
__global__ __launch_bounds__(256) void softmax512_k(const float* __restrict__ sc,
                                                    unsigned short* __restrict__ out) {
  const long n = blockIdx.x;
  const float2* row = (const float2*)(sc + n * 512);
  const int t = threadIdx.x;
  float2 v = row[t];
  float mx = fmaxf(v.x, v.y);
#pragma unroll
  for (int o = 32; o > 0; o >>= 1) mx = fmaxf(mx, __shfl_down(mx, o));
  __shared__ float red[4];
  __shared__ float bm, bz;
  if ((t & 63) == 0) red[t >> 6] = mx;
  __syncthreads();
  if (t == 0) bm = fmaxf(fmaxf(red[0], red[1]), fmaxf(red[2], red[3]));
  __syncthreads();
  const float M = bm;
  const float e0 = expf(v.x - M), e1 = expf(v.y - M);
  float s = e0 + e1;
#pragma unroll
  for (int o = 32; o > 0; o >>= 1) s += __shfl_down(s, o);
  if ((t & 63) == 0) red[t >> 6] = s;
  __syncthreads();
  if (t == 0) bz = 1.f / (red[0] + red[1] + red[2] + red[3]);
  __syncthreads();
  ushort2 u; u.x = f2bf(e0 * bz); u.y = f2bf(e1 * bz);
  *(ushort2*)(out + n * 512 + t * 2) = u;
}

__global__ __launch_bounds__(256) void gate_k(const float* __restrict__ xn,
                                              const float* __restrict__ gw,
                                              const float* __restrict__ gb,
                                              float* __restrict__ gate) {
  const long n = blockIdx.x;
  const int t = threadIdx.x;
  const float4 v = ((const float4*)(xn + n * 1024))[t];
  const float4 g = ((const float4*)gw)[t];
  float s = v.x * g.x + v.y * g.y + v.z * g.z + v.w * g.w;
#pragma unroll
  for (int o = 32; o > 0; o >>= 1) s += __shfl_down(s, o);
  __shared__ float red[4];
  if ((t & 63) == 0) red[t >> 6] = s;
  __syncthreads();
  if (t == 0) {
    const float tot = red[0] + red[1] + red[2] + red[3] + gb[0];
    gate[n] = 1.f / (1.f + expf(-tot));
  }
}

extern "C" void kernel_launch(void* const* d_in, const int* in_sizes, int n_in,
                              void* d_out, int out_size, void* d_ws, size_t ws_size,
                              hipStream_t stream) {
  (void)in_sizes; (void)n_in; (void)out_size; (void)ws_size;
  const float* x    = (const float*)d_in[0];
  const float* prim = (const float*)d_in[1];
  const float* n1w  = (const float*)d_in[2];
  const float* qkvw = (const float*)d_in[3];
  const float* aow  = (const float*)d_in[4];
  const float* n2w  = (const float*)d_in[5];
  const float* rw   = (const float*)d_in[6];
  const float* w1   = (const float*)d_in[7];
  const float* w2   = (const float*)d_in[8];
  const float* n3w  = (const float*)d_in[9];
  const float* tqw  = (const float*)d_in[10];
  const float* tkw  = (const float*)d_in[11];
  const float* tvw  = (const float*)d_in[12];
  const float* tow  = (const float*)d_in[13];
  const float* tgw  = (const float*)d_in[14];
  const float* tgb  = (const float*)d_in[15];

  float* xbuf = (float*)d_out;
  float* aux  = xbuf + 4194304;

  char* W = (char*)d_ws;
  float* xn            = (float*)W;                           // 16 MB
  unsigned short* xnb  = (unsigned short*)(W + (16u << 20));  // 8 MB (hi)
  unsigned short* xnl  = (unsigned short*)(W + (24u << 20));  // 8 MB (lo)
  char* P = W + (32u << 20);

  // phase A
  unsigned short* qh   = (unsigned short*)(P + (48u << 20));
  unsigned short* ql   = (unsigned short*)(P + (56u << 20));
  unsigned short* kh   = (unsigned short*)(P + (64u << 20));
  unsigned short* kl   = (unsigned short*)(P + (72u << 20));
  unsigned short* vh   = (unsigned short*)(P + (80u << 20));
  unsigned short* vl   = (unsigned short*)(P + (88u << 20));
  unsigned short* vth  = (unsigned short*)(P + (96u << 20));   // V^T hi (8 MB)
  unsigned short* vtl  = (unsigned short*)(P + (104u << 20));  // V^T lo (8 MB)
  unsigned short* axh  = (unsigned short*)(P + (112u << 20));
  unsigned short* axl  = (unsigned short*)(P + (120u << 20));
  unsigned short* qwh  = (unsigned short*)(P + (128u << 20));
  unsigned short* qwl  = (unsigned short*)(P + (134u << 20));
  unsigned short* aoh  = (unsigned short*)(P + (140u << 20));
  unsigned short* aol  = (unsigned short*)(P + (142u << 20));
  // phase B (aliases phase A)
  int*   topi = (int*)P;
  float* topw = (float*)(P + 65536);
  int*   slot = (int*)(P + 131072);
  int*   keep = (int*)(P + 196608);
  float* cnt  = (float*)(P + 262144);
  float* psum = (float*)(P + 262144 + 4096);
  int*   s2t  = (int*)(P + 327680);
  float* s2w  = (float*)(P + 393216);
  float* probs = (float*)(P + 458752);                        // 256 KB
  unsigned short* bufb = (unsigned short*)(P + (1u << 20));   // 21 MB
  unsigned short* hb   = (unsigned short*)(P + (22u << 20));  // 42 MB
  unsigned short* Wt   = (unsigned short*)(P + (64u << 20));  // 67 MB
  // phase C (aliases again)
  unsigned short* tqb  = (unsigned short*)P;
  unsigned short* tkb  = (unsigned short*)(P + (2u << 20));
  unsigned short* tvtb = (unsigned short*)(P + (3u << 20));
  float*          tsc  = (float*)(P + (4u << 20));
  unsigned short* tpb  = (unsigned short*)(P + (12u << 20));
  unsigned short* tavb = (unsigned short*)(P + (16u << 20));
  float*          gate = (float*)(P + (18u << 20));
  unsigned short* tqwb = (unsigned short*)(P + (19u << 20));
  unsigned short* tkwb = (unsigned short*)(P + (20u << 20));
  unsigned short* tvwb = (unsigned short*)(P + (21u << 20));
  unsigned short* towb = (unsigned short*)(P + (22u << 20));
  unsigned short* primb= (unsigned short*)(P + (23u << 20));

  // ---- phase A: x += rope_attention(rmsnorm(x)) ----
  rmsnorm_k<0, 1><<<4096, 256, 0, stream>>>(x, n1w, nullptr, xnb, xnl);
  split2_k<<<4096, 256, 0, stream>>>(qkvw, qwh, qwl, aow, aoh, aol);
  bgemm_s<3><<<dim3(24, 32, 1), 256, 0, stream>>>(xnb, xnl, qwh, qwl, nullptr,
      4096, 3072, 1024, nullptr, qh, ql, kh, kl, vh, vl);
  cvt_tb_k<<<dim3(2, 64, 64), 256, 0, stream>>>(vh, vth, vl, vtl);
  flash_k<<<dim3(32, 32), 256, 0, stream>>>(qh, ql, kh, kl, vth, vtl, axh, axl);
  bgemm_s<2><<<dim3(8, 32, 1), 256, 0, stream>>>(axh, axl, aoh, aol, xbuf,
      4096, 1024, 1024, x, nullptr, nullptr, nullptr, nullptr, nullptr, nullptr);

  // ---- phase B: MoE ----
  rmsnorm_k<1, 0><<<4096, 256, 0, stream>>>(xbuf, n2w, xn, xnb, nullptr);
  router_k<<<4096, 256, 0, stream>>>(xn, rw, topi, topw, probs);
  psum_k<<<1, 256, 0, stream>>>(probs, psum);
  pos_k<<<1, 256, 0, stream>>>(topi, topw, slot, keep, s2t, s2w, cnt);
  scatter_b_k<<<8192, 128, 0, stream>>>(xnb, topi, slot, keep, bufb);
  cvt_t_k<<<dim3(64, 32, 16), 256, 0, stream>>>(w1, Wt, 1024, 2048);
  bgemm<3><<<dim3(16, 5, 16), 256, 0, stream>>>(bufb, Wt, hb, 640, 2048, 1024,
      (long)640 * 1024, (long)2048 * 1024, (long)640 * 2048, 1.f, nullptr, nullptr, nullptr);
  cvt_t_k<<<dim3(32, 64, 16), 256, 0, stream>>>(w2, Wt, 2048, 1024);
  bgemm<5><<<dim3(8, 5, 16), 256, 0, stream>>>(hb, Wt, xbuf, 640, 1024, 2048,
      (long)640 * 2048, (long)1024 * 2048, 0, 1.f, nullptr, s2t, s2w);
  aux_k<<<1, 64, 0, stream>>>(cnt, psum, aux);

  // ---- phase C: tou cross-attn ----
  rmsnorm_k<1, 0><<<4096, 256, 0, stream>>>(xbuf, n3w, xn, xnb, nullptr);
  cvt5_k<<<768, 256, 0, stream>>>(tqw, tqwb, tkw, tkwb, tvw, tvwb, tow, towb, prim, primb);
  bgemm<2><<<dim3(2, 32, 1), 256, 0, stream>>>(xnb, tqwb, tqb, 4096, 256, 1024, 0, 0, 0, 1.f, nullptr, nullptr, nullptr);
  bgemm<2><<<dim3(2, 4, 1), 256, 0, stream>>>(primb, tkwb, tkb, 512, 256, 256, 0, 0, 0, 1.f, nullptr, nullptr, nullptr);
  bgemm<2><<<dim3(4, 2, 1), 256, 0, stream>>>(tvwb, primb, tvtb, 256, 512, 256, 0, 0, 0, 1.f, nullptr, nullptr, nullptr);
  bgemm<0><<<dim3(4, 32, 1), 256, 0, stream>>>(tqb, tkb, tsc, 4096, 512, 256, 0, 0, 0, 0.0625f, nullptr, nullptr, nullptr);
  softmax512_k<<<4096, 256, 0, stream>>>(tsc, tpb);
  bgemm<2><<<dim3(2, 32, 1), 256, 0, stream>>>(tpb, tvtb, tavb, 4096, 256, 512, 0, 0, 0, 1.f, nullptr, nullptr, nullptr);
  gate_k<<<4096, 256, 0, stream>>>(xn, tgw, tgb, gate);
  bgemm<4><<<dim3(8, 32, 1), 256, 0, stream>>>(tavb, towb, xbuf, 4096, 1024, 256, 0, 0, 0, 1.f, gate, nullptr, nullptr);
}

// Round 5
// 886.035 us; speedup vs baseline: 1.3116x; 1.0863x over previous
//
#include <hip/hip_runtime.h>
#include <math.h>

// B=2 T=2048 D=1024 H=16 DH=64 E=16 K=2 F=2048 CAP=640 DP=256 NPRIM=512
typedef short bf16x8 __attribute__((ext_vector_type(8)));
typedef float f32x4 __attribute__((ext_vector_type(4)));

__device__ __forceinline__ unsigned short f2bf(float f) {
  union { float f; unsigned u; } v; v.f = f;
  return (unsigned short)((v.u + 0x7fff + ((v.u >> 16) & 1)) >> 16);
}
__device__ __forceinline__ float bf2f(unsigned short h) {
  union { unsigned u; float f; } v; v.u = ((unsigned)h) << 16;
  return v.f;
}

// Direct global->LDS DMA, 16B per lane. LDS dest is wave-uniform base + lane*16.
__device__ __forceinline__ void gld16(const unsigned short* g, unsigned short* l) {
  __builtin_amdgcn_global_load_lds((const __attribute__((address_space(1))) void*)g,
                                   (__attribute__((address_space(3))) void*)l, 16, 0, 0);
}

// ---------------- RMSNorm: optional fp32 out, bf16-hi out, optional bf16-lo out ----------------
template <int WF32, int WLO>
__global__ __launch_bounds__(256) void rmsnorm_k(const float* __restrict__ x,
                                                 const float* __restrict__ w,
                                                 float* __restrict__ y,
                                                 unsigned short* __restrict__ yb,
                                                 unsigned short* __restrict__ yl) {
  const long n = blockIdx.x;
  const int t = threadIdx.x;
  const float4 v = ((const float4*)(x + n * 1024))[t];
  float ss = v.x * v.x + v.y * v.y + v.z * v.z + v.w * v.w;
#pragma unroll
  for (int o = 32; o > 0; o >>= 1) ss += __shfl_down(ss, o);
  __shared__ float red[4];
  __shared__ float sc;
  if ((t & 63) == 0) red[t >> 6] = ss;
  __syncthreads();
  if (t == 0) sc = rsqrtf((red[0] + red[1] + red[2] + red[3]) * (1.0f / 1024.0f) + 1e-6f);
  __syncthreads();
  const float s = sc;
  const float4 wv = ((const float4*)w)[t];
  float4 o;
  o.x = v.x * s * wv.x; o.y = v.y * s * wv.y; o.z = v.z * s * wv.z; o.w = v.w * s * wv.w;
  if (WF32) ((float4*)(y + n * 1024))[t] = o;
  ushort4 u = make_ushort4(f2bf(o.x), f2bf(o.y), f2bf(o.z), f2bf(o.w));
  *(ushort4*)(yb + n * 1024 + t * 4) = u;
  if (WLO) {
    ushort4 l = make_ushort4(f2bf(o.x - bf2f(u.x)), f2bf(o.y - bf2f(u.y)),
                             f2bf(o.z - bf2f(u.z)), f2bf(o.w - bf2f(u.w)));
    *(ushort4*)(yl + n * 1024 + t * 4) = l;
  }
}

// ---------------- fused weight hi/lo splits: qkvw (786432 f4) + aow (262144 f4) ----------------
__global__ __launch_bounds__(256) void split2_k(const float* __restrict__ s0,
                                                unsigned short* __restrict__ h0,
                                                unsigned short* __restrict__ l0,
                                                const float* __restrict__ s1,
                                                unsigned short* __restrict__ h1,
                                                unsigned short* __restrict__ l1) {
  const int i = blockIdx.x * 256 + threadIdx.x;  // 4096*256 = 1048576 float4 groups
  const float* s; unsigned short* hp; unsigned short* lp; int off;
  if (i < 786432) { s = s0; hp = h0; lp = l0; off = i; }
  else            { s = s1; hp = h1; lp = l1; off = i - 786432; }
  const float4 v = ((const float4*)s)[off];
  ushort4 h = make_ushort4(f2bf(v.x), f2bf(v.y), f2bf(v.z), f2bf(v.w));
  ushort4 l = make_ushort4(f2bf(v.x - bf2f(h.x)), f2bf(v.y - bf2f(h.y)),
                           f2bf(v.z - bf2f(h.z)), f2bf(v.w - bf2f(h.w)));
  ((ushort4*)hp)[off] = h;
  ((ushort4*)lp)[off] = l;
}

// ---------------- fused phase-C weight conversions (5 regions, 1 launch) ----------------
__global__ __launch_bounds__(256) void cvt5_k(const float* __restrict__ s0, unsigned short* __restrict__ d0,
                                              const float* __restrict__ s1, unsigned short* __restrict__ d1,
                                              const float* __restrict__ s2, unsigned short* __restrict__ d2,
                                              const float* __restrict__ s3, unsigned short* __restrict__ d3,
                                              const float* __restrict__ s4, unsigned short* __restrict__ d4) {
  const int i = blockIdx.x * 256 + threadIdx.x;  // 768*256 = 196608 float4 groups total
  const float* s; unsigned short* d; int off;
  if (i < 65536)       { s = s0; d = d0; off = i; }
  else if (i < 81920)  { s = s1; d = d1; off = i - 65536; }
  else if (i < 98304)  { s = s2; d = d2; off = i - 81920; }
  else if (i < 163840) { s = s3; d = d3; off = i - 98304; }
  else                 { s = s4; d = d4; off = i - 163840; }
  const float4 v = ((const float4*)s)[off];
  ((ushort4*)d)[off] = make_ushort4(f2bf(v.x), f2bf(v.y), f2bf(v.z), f2bf(v.w));
}

// ---------------- transpose-convert: (R,C) fp32 -> (C,R) bf16, batched ----------------
__global__ __launch_bounds__(256) void cvt_t_k(const float* __restrict__ in,
                                               unsigned short* __restrict__ out,
                                               int R, int C) {
  in += (size_t)blockIdx.z * R * C;
  out += (size_t)blockIdx.z * R * C;
  const int r0 = blockIdx.y * 32, c0 = blockIdx.x * 32;
  __shared__ float T[32][33];
  const int tid = threadIdx.x;
  const int li = tid >> 3;
  const int lj = (tid & 7) << 2;
  const float4 v = *(const float4*)(in + (size_t)(r0 + li) * C + c0 + lj);
  T[li][lj + 0] = v.x; T[li][lj + 1] = v.y; T[li][lj + 2] = v.z; T[li][lj + 3] = v.w;
  __syncthreads();
  ushort4 u = make_ushort4(f2bf(T[lj + 0][li]), f2bf(T[lj + 1][li]),
                           f2bf(T[lj + 2][li]), f2bf(T[lj + 3][li]));
  *(ushort4*)(out + (size_t)(c0 + li) * R + r0 + lj) = u;
}

// ---------------- bf16 transpose: per z, (2048,64) -> (64,2048); z<32: pair0, else pair1 ----------------
__global__ __launch_bounds__(256) void cvt_tb_k(const unsigned short* __restrict__ in0,
                                                unsigned short* __restrict__ out0,
                                                const unsigned short* __restrict__ in1,
                                                unsigned short* __restrict__ out1) {
  const int zz = blockIdx.z;
  const unsigned short* in = (zz < 32 ? in0 : in1) + (size_t)(zz & 31) * 2048 * 64;
  unsigned short* out = (zz < 32 ? out0 : out1) + (size_t)(zz & 31) * 2048 * 64;
  const int r0 = blockIdx.y * 32, c0 = blockIdx.x * 32;
  __shared__ unsigned short T[32][36];
  const int tid = threadIdx.x;
  const int li = tid >> 3;
  const int lj = (tid & 7) << 2;
  const ushort4 v = *(const ushort4*)(in + (size_t)(r0 + li) * 64 + c0 + lj);
  T[li][lj + 0] = v.x; T[li][lj + 1] = v.y; T[li][lj + 2] = v.z; T[li][lj + 3] = v.w;
  __syncthreads();
  ushort4 u = make_ushort4(T[lj + 0][li], T[lj + 1][li], T[lj + 2][li], T[lj + 3][li]);
  *(ushort4*)(out + (size_t)(c0 + li) * 2048 + r0 + lj) = u;
}

// ---------------- bf16 MFMA GEMM: C(M,N) = alpha * A(M,K) x B(N,K)^T ----------------
// m97 structure: linear LDS + global_load_lds width-16 staging (no reg round-trip).
// MODE: 0=f32 store, 1=f32 +=, 2=bf16 store, 3=bf16 silu store,
//       4=f32 += rowscale[row]*v, 5=f32 atomicAdd to rowmap token (MoE un-scatter)
template <int MODE>
__global__ __launch_bounds__(256) void bgemm(const unsigned short* __restrict__ A,
                                             const unsigned short* __restrict__ B,
                                             void* __restrict__ Cv,
                                             int M, int N, int K,
                                             long sA, long sB, long sC, float alpha,
                                             const float* __restrict__ rowscale,
                                             const int* __restrict__ rowmap,
                                             const float* __restrict__ roww) {
  __shared__ __align__(16) unsigned short As[128 * 32];
  __shared__ __align__(16) unsigned short Bs[128 * 32];
  const int tid = threadIdx.x;
  const int z = blockIdx.z;
  const unsigned short* Ag = A + (size_t)z * sA;
  const unsigned short* Bg = B + (size_t)z * sB;
  const int m0 = blockIdx.y * 128, n0 = blockIdx.x * 128;
  const int lane = tid & 63;
  const int wid = tid >> 6;
  const int wm = (wid >> 1) * 64, wn = (wid & 1) * 64;
  const int fr = lane & 15, fq = lane >> 4;
  const int lr = tid >> 2, lk = (tid & 3) * 8;
  f32x4 acc[4][4] = {};
  const unsigned short* Ap0 = Ag + (size_t)(m0 + lr) * K + lk;
  const unsigned short* Ap1 = Ag + (size_t)(m0 + lr + 64) * K + lk;
  const unsigned short* Bp0 = Bg + (size_t)(n0 + lr) * K + lk;
  const unsigned short* Bp1 = Bg + (size_t)(n0 + lr + 64) * K + lk;
  unsigned short* Asw = As + wid * 512;  // wave-uniform LDS base (bytes: wid*1024)
  unsigned short* Bsw = Bs + wid * 512;
  gld16(Ap0, Asw); gld16(Ap1, Asw + 2048);
  gld16(Bp0, Bsw); gld16(Bp1, Bsw + 2048);
  for (int k0 = 0;;) {
    __syncthreads();  // drains vmcnt: staged tile visible to all waves
    bf16x8 af[4], bv[4];
#pragma unroll
    for (int i = 0; i < 4; ++i) af[i] = *(const bf16x8*)&As[(wm + i * 16 + fr) * 32 + fq * 8];
#pragma unroll
    for (int j = 0; j < 4; ++j) bv[j] = *(const bf16x8*)&Bs[(wn + j * 16 + fr) * 32 + fq * 8];
    __syncthreads();  // all frag reads done -> safe to overwrite tile
    k0 += 32;
    if (k0 < K) {     // next-tile DMA overlaps the MFMAs below
      gld16(Ap0 + k0, Asw); gld16(Ap1 + k0, Asw + 2048);
      gld16(Bp0 + k0, Bsw); gld16(Bp1 + k0, Bsw + 2048);
    }
#pragma unroll
    for (int i = 0; i < 4; ++i)
#pragma unroll
      for (int j = 0; j < 4; ++j)
        acc[i][j] = __builtin_amdgcn_mfma_f32_16x16x32_bf16(af[i], bv[j], acc[i][j], 0, 0, 0);
    if (k0 >= K) break;
  }
#pragma unroll
  for (int i = 0; i < 4; ++i) {
#pragma unroll
    for (int reg = 0; reg < 4; ++reg) {
      const int row = m0 + wm + i * 16 + fq * 4 + reg;
      float rs = 0.f, wgt = 0.f;
      int tok = -1;
      if (MODE == 4) rs = rowscale[row];
      if (MODE == 5) {
        tok = rowmap[z * M + row];
        if (tok >= 0) wgt = roww[z * M + row];
      }
#pragma unroll
      for (int j = 0; j < 4; ++j) {
        const int col = n0 + wn + j * 16 + fr;
        const float v = alpha * acc[i][j][reg];
        if (MODE == 0) {
          ((float*)Cv + (size_t)z * sC)[(size_t)row * N + col] = v;
        } else if (MODE == 1) {
          float* p = (float*)Cv + (size_t)z * sC + (size_t)row * N + col;
          *p += v;
        } else if (MODE == 2) {
          ((unsigned short*)Cv + (size_t)z * sC)[(size_t)row * N + col] = f2bf(v);
        } else if (MODE == 3) {
          const float sv = v / (1.f + __expf(-v));
          ((unsigned short*)Cv + (size_t)z * sC)[(size_t)row * N + col] = f2bf(sv);
        } else if (MODE == 4) {
          float* p = (float*)Cv + (size_t)row * N + col;
          *p += rs * v;
        } else if (MODE == 5) {
          if (tok >= 0) atomicAdd((float*)Cv + (size_t)tok * N + col, wgt * v);
        }
      }
    }
  }
}

// ---------------- Fused split-bf16 GEMM: C = (Ah+Al)(Bh+Bl)^T (3-term) ----------------
// MODE: 0 = f32 store, 1 = f32 +=, 2 = f32 store of res[row,col] + v (residual fuse),
//       3 = fused RoPE + hi/lo split QKV output to [bh][t][dh] (no C)
template <int MODE>
__global__ __launch_bounds__(256) void bgemm_s(const unsigned short* __restrict__ Ah,
                                               const unsigned short* __restrict__ Al,
                                               const unsigned short* __restrict__ Bh,
                                               const unsigned short* __restrict__ Bl,
                                               float* __restrict__ C,
                                               int M, int N, int K,
                                               const float* __restrict__ res,
                                               unsigned short* __restrict__ Qh,
                                               unsigned short* __restrict__ Ql,
                                               unsigned short* __restrict__ Kh,
                                               unsigned short* __restrict__ Kl,
                                               unsigned short* __restrict__ Vh,
                                               unsigned short* __restrict__ Vl) {
  __shared__ __align__(16) unsigned short Ash[128 * 32];
  __shared__ __align__(16) unsigned short Asl[128 * 32];
  __shared__ __align__(16) unsigned short Bsh[128 * 32];
  __shared__ __align__(16) unsigned short Bsl[128 * 32];
  const int tid = threadIdx.x;
  const int m0 = blockIdx.y * 128, n0 = blockIdx.x * 128;
  const int lane = tid & 63;
  const int wid = tid >> 6;
  const int wm = (wid >> 1) * 64, wn = (wid & 1) * 64;
  const int fr = lane & 15, fq = lane >> 4;
  const int lr = tid >> 2, lk = (tid & 3) * 8;
  f32x4 acc[4][4] = {};
  const size_t oA0 = (size_t)(m0 + lr) * K + lk, oA1 = (size_t)(m0 + lr + 64) * K + lk;
  const size_t oB0 = (size_t)(n0 + lr) * K + lk, oB1 = (size_t)(n0 + lr + 64) * K + lk;
  const int wb = wid * 512;
  gld16(Ah + oA0, Ash + wb); gld16(Ah + oA1, Ash + wb + 2048);
  gld16(Al + oA0, Asl + wb); gld16(Al + oA1, Asl + wb + 2048);
  gld16(Bh + oB0, Bsh + wb); gld16(Bh + oB1, Bsh + wb + 2048);
  gld16(Bl + oB0, Bsl + wb); gld16(Bl + oB1, Bsl + wb + 2048);
  for (int k0 = 0;;) {
    __syncthreads();
    bf16x8 afh[4], afl[4], bvh[4], bvl[4];
#pragma unroll
    for (int i = 0; i < 4; ++i) {
      afh[i] = *(const bf16x8*)&Ash[(wm + i * 16 + fr) * 32 + fq * 8];
      afl[i] = *(const bf16x8*)&Asl[(wm + i * 16 + fr) * 32 + fq * 8];
    }
#pragma unroll
    for (int j = 0; j < 4; ++j) {
      bvh[j] = *(const bf16x8*)&Bsh[(wn + j * 16 + fr) * 32 + fq * 8];
      bvl[j] = *(const bf16x8*)&Bsl[(wn + j * 16 + fr) * 32 + fq * 8];
    }
    __syncthreads();
    k0 += 32;
    if (k0 < K) {
      gld16(Ah + oA0 + k0, Ash + wb); gld16(Ah + oA1 + k0, Ash + wb + 2048);
      gld16(Al + oA0 + k0, Asl + wb); gld16(Al + oA1 + k0, Asl + wb + 2048);
      gld16(Bh + oB0 + k0, Bsh + wb); gld16(Bh + oB1 + k0, Bsh + wb + 2048);
      gld16(Bl + oB0 + k0, Bsl + wb); gld16(Bl + oB1 + k0, Bsl + wb + 2048);
    }
#pragma unroll
    for (int j = 0; j < 4; ++j) {
#pragma unroll
      for (int i = 0; i < 4; ++i) {
        acc[i][j] = __builtin_amdgcn_mfma_f32_16x16x32_bf16(afl[i], bvh[j], acc[i][j], 0, 0, 0);
        acc[i][j] = __builtin_amdgcn_mfma_f32_16x16x32_bf16(afh[i], bvl[j], acc[i][j], 0, 0, 0);
        acc[i][j] = __builtin_amdgcn_mfma_f32_16x16x32_bf16(afh[i], bvh[j], acc[i][j], 0, 0, 0);
      }
    }
    if (k0 >= K) break;
  }
  if (MODE == 3) {
    // Fused RoPE + hi/lo split. Each (i,reg) holds cols d = fr, fr+16, fr+32, fr+48 of
    // ONE head-band (n0+wn is 64-aligned; 1024%64==0 so band never crosses q/k/v).
    const int band = n0 + wn;
    const int which = band >> 10;           // 0=q 1=k 2=v
    const int h = (band & 1023) >> 6;
    unsigned short* Hp = (which == 0) ? Qh : ((which == 1) ? Kh : Vh);
    unsigned short* Lp = (which == 0) ? Ql : ((which == 1) ? Kl : Vl);
    const float l2t = 13.287712379549449f;  // log2(10000)
    const float inv0 = exp2f(-l2t * (float)fr * (1.0f / 32.0f));
    const float inv1 = exp2f(-l2t * (float)(fr + 16) * (1.0f / 32.0f));
#pragma unroll
    for (int i = 0; i < 4; ++i) {
#pragma unroll
      for (int reg = 0; reg < 4; ++reg) {
        const int row = m0 + wm + i * 16 + fq * 4 + reg;
        const int b = row >> 11, t = row & 2047;
        float o0 = acc[i][0][reg], o1 = acc[i][1][reg];
        float o2 = acc[i][2][reg], o3 = acc[i][3][reg];
        if (which != 2) {
          const float a0 = (float)t * inv0, a1 = (float)t * inv1;
          const float c0 = cosf(a0), sn0 = sinf(a0);
          const float c1 = cosf(a1), sn1 = sinf(a1);
          const float v0 = o0, v1 = o1, v2 = o2, v3 = o3;
          o0 = v0 * c0 - v2 * sn0;   // d = fr        (<32): pair +32 negated
          o1 = v1 * c1 - v3 * sn1;   // d = fr+16
          o2 = v2 * c0 + v0 * sn0;   // d = fr+32     (>=32): pair -32
          o3 = v3 * c1 + v1 * sn1;   // d = fr+48
        }
        const long bo = ((long)((b << 4) + h) * 2048 + t) * 64 + fr;
        const unsigned short h0 = f2bf(o0), h1 = f2bf(o1);
        const unsigned short h2 = f2bf(o2), h3 = f2bf(o3);
        Hp[bo] = h0; Hp[bo + 16] = h1; Hp[bo + 32] = h2; Hp[bo + 48] = h3;
        Lp[bo]      = f2bf(o0 - bf2f(h0));
        Lp[bo + 16] = f2bf(o1 - bf2f(h1));
        Lp[bo + 32] = f2bf(o2 - bf2f(h2));
        Lp[bo + 48] = f2bf(o3 - bf2f(h3));
      }
    }
  } else {
#pragma unroll
    for (int i = 0; i < 4; ++i) {
#pragma unroll
      for (int reg = 0; reg < 4; ++reg) {
        const int row = m0 + wm + i * 16 + fq * 4 + reg;
#pragma unroll
        for (int j = 0; j < 4; ++j) {
          const int col = n0 + wn + j * 16 + fr;
          float* p = C + (size_t)row * N + col;
          if (MODE == 0) *p = acc[i][j][reg];
          else if (MODE == 1) *p += acc[i][j][reg];
          else *p = res[(size_t)row * N + col] + acc[i][j][reg];
        }
      }
    }
  }
}

// ---------------- Split-bf16 MFMA flash attention, v4: paired q-tiles ----------------
// Causal-triangle load balance: block x handles q-tiles (31-x) and (x) sequentially
// -> every block runs exactly 33 KV-tile iterations; 512 equal blocks = steady
// 2 blocks/CU residency with no drain tail (fixes time-avg occupancy 13.8%).
// K and V^T staged by global_load_lds with pre-swizzled SOURCE (linear LDS dest).
__global__ __launch_bounds__(256) void flash_k(const unsigned short* __restrict__ Qhg,
                                               const unsigned short* __restrict__ Qlg,
                                               const unsigned short* __restrict__ Khg,
                                               const unsigned short* __restrict__ Klg,
                                               const unsigned short* __restrict__ Vthg,
                                               const unsigned short* __restrict__ Vtlg,
                                               unsigned short* __restrict__ axh,
                                               unsigned short* __restrict__ axl) {
  const int bh = blockIdx.y;
  const int b = bh >> 4, h = bh & 15;
  __shared__ __align__(16) unsigned short Ksh[64 * 64];
  __shared__ __align__(16) unsigned short Ksl[64 * 64];
  __shared__ __align__(16) unsigned short Vth[64 * 64];  // V^T: row d, col t (swizzled)
  __shared__ __align__(16) unsigned short Vtl[64 * 64];
  __shared__ __align__(16) unsigned short Psh[4 * 16 * 64];
  __shared__ __align__(16) unsigned short Psl[4 * 16 * 64];
  const int tid = threadIdx.x;
  const int w = tid >> 6;
  const int lane = tid & 63;
  const int fr = lane & 15, fq = lane >> 4;
  const long kv_base = (long)bh * 2048 * 64;  // K: [bh][t][64]; V^T: [bh][d][2048]

  for (int pass = 0; pass < 2; ++pass) {
    const int qb = pass == 0 ? (31 - (int)blockIdx.x) : (int)blockIdx.x;
    const int q0 = qb << 6;
    const long base_q = ((long)bh * 2048 + q0) * 64;
    // Q in registers (per-wave static fragments)
    bf16x8 qh_r[2], ql_r[2];
#pragma unroll
    for (int kc = 0; kc < 2; ++kc) {
      qh_r[kc] = *(const bf16x8*)(Qhg + base_q + (w * 16 + fr) * 64 + kc * 32 + fq * 8);
      ql_r[kc] = *(const bf16x8*)(Qlg + base_q + (w * 16 + fr) * 64 + kc * 32 + fq * 8);
    }
    f32x4 o_acc[4] = {};
    float m_st[4], l_st[4];
#pragma unroll
    for (int i = 0; i < 4; ++i) { m_st[i] = -3.0e38f; l_st[i] = 0.f; }

    // ---- prologue: stage K(0), V^T(0) ----
    __syncthreads();  // pass>0: ensure all waves' prior-pass PV/LDS reads are done
#pragma unroll
    for (int rep = 0; rep < 2; ++rep) {
      const int f = tid + rep * 256;
      const int r = f >> 3, c = f & 7;
      const long srcK = kv_base + r * 64 + ((c ^ (r & 7)) * 8);
      gld16(Khg + srcK, Ksh + f * 8);
      gld16(Klg + srcK, Ksl + f * 8);
      const long srcV = kv_base + (long)r * 2048 + ((c ^ (r & 7)) * 8);  // d=r, t0=0
      gld16(Vthg + srcV, Vth + f * 8);
      gld16(Vtlg + srcV, Vtl + f * 8);
    }
    __syncthreads();  // drains all DMA

    for (int kb = 0;; ++kb) {
      const bool more = (kb < qb);
      // ---- 1. QK^T (reads Ksh/Ksl + Q regs) ----
      f32x4 sfr[4] = {};
      __builtin_amdgcn_s_setprio(1);
#pragma unroll
      for (int kc = 0; kc < 2; ++kc) {
#pragma unroll
        for (int j = 0; j < 4; ++j) {
          const int co = (j * 16 + fr) * 64 + ((kc * 32 + fq * 8) ^ ((fr & 7) << 3));
          const bf16x8 kh_ = *(const bf16x8*)&Ksh[co];
          const bf16x8 kl_ = *(const bf16x8*)&Ksl[co];
          sfr[j] = __builtin_amdgcn_mfma_f32_16x16x32_bf16(ql_r[kc], kh_, sfr[j], 0, 0, 0);
          sfr[j] = __builtin_amdgcn_mfma_f32_16x16x32_bf16(qh_r[kc], kl_, sfr[j], 0, 0, 0);
          sfr[j] = __builtin_amdgcn_mfma_f32_16x16x32_bf16(qh_r[kc], kh_, sfr[j], 0, 0, 0);
        }
      }
      __builtin_amdgcn_s_setprio(0);
      // ---- 2. online softmax + P -> LDS (wave-local region) ----
      const bool diag = (kb == qb);
      float p[4][4];
      float alpha[4];
#pragma unroll
      for (int reg = 0; reg < 4; ++reg) {
        const int qloc = w * 16 + fq * 4 + reg;
        float v[4];
#pragma unroll
        for (int j = 0; j < 4; ++j) {
          float s = sfr[j][reg] * 0.125f;
          if (diag && (j * 16 + fr) > qloc) s = -1.0e30f;
          v[j] = s;
        }
        float mt = fmaxf(fmaxf(v[0], v[1]), fmaxf(v[2], v[3]));
#pragma unroll
        for (int off = 1; off < 16; off <<= 1) mt = fmaxf(mt, __shfl_xor(mt, off));
        const float mn = fmaxf(m_st[reg], mt);
        alpha[reg] = __expf(m_st[reg] - mn);
        m_st[reg] = mn;
        float ps = 0.f;
#pragma unroll
        for (int j = 0; j < 4; ++j) { p[j][reg] = __expf(v[j] - mn); ps += p[j][reg]; }
#pragma unroll
        for (int off = 1; off < 16; off <<= 1) ps += __shfl_xor(ps, off);
        l_st[reg] = l_st[reg] * alpha[reg] + ps;
      }
#pragma unroll
      for (int reg = 0; reg < 4; ++reg) {
        const int qp = fq * 4 + reg;
#pragma unroll
        for (int j = 0; j < 4; ++j) {
          const float pv = p[j][reg];
          const unsigned short ph = f2bf(pv);
          const unsigned short pl = f2bf(pv - bf2f(ph));
          const int sa = w * 1024 + qp * 64 + ((j * 16 + fr) ^ ((qp & 7) << 3));
          Psh[sa] = ph;
          Psl[sa] = pl;
        }
      }
#pragma unroll
      for (int j = 0; j < 4; ++j)
#pragma unroll
        for (int reg = 0; reg < 4; ++reg) o_acc[j][reg] *= alpha[reg];
      // ---- 3. barrier A: K(kb) reads + P writes done; drains V-DMA(kb) ----
      __syncthreads();
      // ---- 4. issue K(kb+1) DMA (overlaps PV; drained at barrier B) ----
      if (more) {
        const long bk = kv_base + (long)((kb + 1) << 6) * 64;
#pragma unroll
        for (int rep = 0; rep < 2; ++rep) {
          const int f = tid + rep * 256;
          const int r = f >> 3, c = f & 7;
          const long src = bk + r * 64 + ((c ^ (r & 7)) * 8);
          gld16(Khg + src, Ksh + f * 8);
          gld16(Klg + src, Ksl + f * 8);
        }
      }
      // ---- 5. PV (reads Vth/Vtl + Psh/Psl) ----
      __builtin_amdgcn_s_setprio(1);
#pragma unroll
      for (int kc = 0; kc < 2; ++kc) {
        const int po = w * 1024 + fr * 64 + ((kc * 32 + fq * 8) ^ ((fr & 7) << 3));
        const bf16x8 ph_ = *(const bf16x8*)&Psh[po];
        const bf16x8 pl_ = *(const bf16x8*)&Psl[po];
#pragma unroll
        for (int j = 0; j < 4; ++j) {
          const int co = (j * 16 + fr) * 64 + ((kc * 32 + fq * 8) ^ ((fr & 7) << 3));
          const bf16x8 vh_ = *(const bf16x8*)&Vth[co];
          const bf16x8 vl_ = *(const bf16x8*)&Vtl[co];
          o_acc[j] = __builtin_amdgcn_mfma_f32_16x16x32_bf16(pl_, vh_, o_acc[j], 0, 0, 0);
          o_acc[j] = __builtin_amdgcn_mfma_f32_16x16x32_bf16(ph_, vl_, o_acc[j], 0, 0, 0);
          o_acc[j] = __builtin_amdgcn_mfma_f32_16x16x32_bf16(ph_, vh_, o_acc[j], 0, 0, 0);
        }
      }
      __builtin_amdgcn_s_setprio(0);
      if (!more) break;
      // ---- 6. barrier B: V(kb)/P(kb) reads done; drains K-DMA(kb+1) ----
      __syncthreads();
      // ---- 7. issue V^T(kb+1) DMA (overlaps next QK+softmax; drained at barrier A) ----
      {
        const int t0 = (kb + 1) << 6;
#pragma unroll
        for (int rep = 0; rep < 2; ++rep) {
          const int f = tid + rep * 256;
          const int d = f >> 3, c = f & 7;
          const long src = kv_base + (long)d * 2048 + t0 + ((c ^ (d & 7)) * 8);
          gld16(Vthg + src, Vth + f * 8);
          gld16(Vtlg + src, Vtl + f * 8);
        }
      }
    }
#pragma unroll
    for (int reg = 0; reg < 4; ++reg) {
      const long tok = (long)b * 2048 + q0 + w * 16 + fq * 4 + reg;
      const float il = 1.f / l_st[reg];
#pragma unroll
      for (int j = 0; j < 4; ++j) {
        const float v = o_acc[j][reg] * il;
        const unsigned short hi = f2bf(v);
        const unsigned short lo = f2bf(v - bf2f(hi));
        const long off = tok * 1024 + h * 64 + j * 16 + fr;
        axh[off] = hi;
        axl[off] = lo;
      }
    }
  }
}

// ---------------- Router: coalesced dot, no atomics, probs to workspace ----------------
__global__ __launch_bounds__(256) void router_k(const float* __restrict__ xn,
                                                const float* __restrict__ rw,
                                                int* __restrict__ topi,
                                                float* __restrict__ topw,
                                                float* __restrict__ probs) {
  const int n = blockIdx.x;
  const int t = threadIdx.x;
  const float4 xv = ((const float4*)(xn + (size_t)n * 1024))[t];
  float acc[16];
#pragma unroll
  for (int e = 0; e < 16; ++e) {
    const float4 wv = ((const float4*)(rw + (size_t)e * 1024))[t];
    acc[e] = xv.x * wv.x + xv.y * wv.y + xv.z * wv.z + xv.w * wv.w;
  }
#pragma unroll
  for (int e = 0; e < 16; ++e)
#pragma unroll
    for (int o = 32; o > 0; o >>= 1) acc[e] += __shfl_down(acc[e], o);
  __shared__ float red[4][16];
  if ((t & 63) == 0) {
#pragma unroll
    for (int e = 0; e < 16; ++e) red[t >> 6][e] = acc[e];
  }
  __syncthreads();
  if (t == 0) {
    float logits[16];
#pragma unroll
    for (int e = 0; e < 16; ++e)
      logits[e] = red[0][e] + red[1][e] + red[2][e] + red[3][e];
    float mx = logits[0];
#pragma unroll
    for (int e = 1; e < 16; ++e) mx = fmaxf(mx, logits[e]);
    float p[16];
    float Z = 0.f;
#pragma unroll
    for (int e = 0; e < 16; ++e) { p[e] = expf(logits[e] - mx); Z += p[e]; }
    const float iz = 1.f / Z;
#pragma unroll
    for (int e = 0; e < 16; ++e) p[e] *= iz;
    int i1 = 0;
#pragma unroll
    for (int e = 1; e < 16; ++e) if (p[e] > p[i1]) i1 = e;
    int i2 = (i1 == 0) ? 1 : 0;
#pragma unroll
    for (int e = 0; e < 16; ++e) if (e != i1 && p[e] > p[i2]) i2 = e;
    const float sw = p[i1] + p[i2];
    topi[2 * n] = i1; topi[2 * n + 1] = i2;
    topw[2 * n] = p[i1] / sw; topw[2 * n + 1] = p[i2] / sw;
    float* pr = probs + (size_t)n * 16;
#pragma unroll
    for (int e = 0; e < 16; ++e) pr[e] = p[e];
  }
}

// ---------------- psum reduction (single block) ----------------
__global__ __launch_bounds__(256) void psum_k(const float* __restrict__ probs,
                                              float* __restrict__ psum) {
  float acc[16] = {};
  for (int n = threadIdx.x; n < 4096; n += 256) {
    const float4* pr = (const float4*)(probs + (size_t)n * 16);
#pragma unroll
    for (int q = 0; q < 4; ++q) {
      const float4 v = pr[q];
      acc[q * 4 + 0] += v.x; acc[q * 4 + 1] += v.y;
      acc[q * 4 + 2] += v.z; acc[q * 4 + 3] += v.w;
    }
  }
#pragma unroll
  for (int e = 0; e < 16; ++e)
#pragma unroll
    for (int o = 32; o > 0; o >>= 1) acc[e] += __shfl_down(acc[e], o);
  __shared__ float red[4][16];
  if ((threadIdx.x & 63) == 0) {
#pragma unroll
    for (int e = 0; e < 16; ++e) red[threadIdx.x >> 6][e] = acc[e];
  }
  __syncthreads();
  if (threadIdx.x < 16)
    psum[threadIdx.x] = red[0][threadIdx.x] + red[1][threadIdx.x] +
                        red[2][threadIdx.x] + red[3][threadIdx.x];
}

// ---------------- Parallel capacity scan (order-exact); also emits cnt ----------------
__global__ __launch_bounds__(256) void pos_k(const int* __restrict__ topi,
                                             const float* __restrict__ topw,
                                             int* __restrict__ slot,
                                             int* __restrict__ keep,
                                             int* __restrict__ s2t,
                                             float* __restrict__ s2w,
                                             float* __restrict__ cnt) {
  __shared__ int fi[8192];
  __shared__ int hist[256][16];
  __shared__ int total[16];
  const int t = threadIdx.x;
  for (int i = t; i < 8192; i += 256) fi[i] = topi[i];
#pragma unroll
  for (int e = 0; e < 16; ++e) hist[t][e] = 0;
  __syncthreads();
  const int base = t * 32;
#pragma unroll 8
  for (int i = 0; i < 32; ++i) hist[t][fi[base + i]]++;
  __syncthreads();
  if (t < 16) {
    int run = 0;
    for (int c = 0; c < 256; ++c) { const int v = hist[c][t]; hist[c][t] = run; run += v; }
    total[t] = run;
    cnt[t] = (float)run;
  }
  __syncthreads();
  int run[16];
#pragma unroll
  for (int e = 0; e < 16; ++e) run[e] = hist[t][e];
  for (int i = 0; i < 32; ++i) {
    const int idx = base + i;
    const int e = fi[idx];
    const int p = run[e]++;
    if (p < 640) {
      slot[idx] = p; keep[idx] = 1;
      s2t[e * 640 + p] = idx >> 1;
      s2w[e * 640 + p] = topw[idx];
    } else {
      slot[idx] = 639; keep[idx] = 0;
    }
  }
  __syncthreads();
  for (int pos = t; pos < 16 * 640; pos += 256) {
    const int e = pos / 640, c = pos - e * 640;
    if (c >= total[e]) s2t[pos] = -1;
  }
}

__global__ __launch_bounds__(128) void scatter_b_k(const unsigned short* __restrict__ xnb,
                                                   const int* __restrict__ topi,
                                                   const int* __restrict__ slot,
                                                   const int* __restrict__ keep,
                                                   unsigned short* __restrict__ buf) {
  const int i = blockIdx.x;
  if (!keep[i]) return;
  const int n = i >> 1;
  const size_t dst = ((size_t)topi[i] * 640 + slot[i]) * 1024;
  ((uint4*)(buf + dst))[threadIdx.x] = ((const uint4*)(xnb + (size_t)n * 1024))[threadIdx.x];
}

__global__ void aux_k(const float* __restrict__ cnt, const float* __restrict__ psum,
                      float* __restrict__ out) {
  if (threadIdx.x == 0) {
    float s = 0.f;
    for (int e = 0; e < 16; ++e)
      s += (cnt[e] * (1.f / 4096.f)) * (psum[e] * (1.f / 4096.f));
    out[0] = 16.f * s;
  }
}

// ---------------- tou softmax (fp32 in -> bf16 probs) + gate ----------------
__global__ __launch_bounds__(256) void softmax512_k(const float* __restrict__ sc,
                                                    unsigned short* __restrict__ out) {
  const long n = blockIdx.x;
  const float2* row = (const float2*)(sc + n * 512);
  const int t = threadIdx.x;
  float2 v = row[t];
  float mx = fmaxf(v.x, v.y);
#pragma unroll
  for (int o = 32; o > 0; o >>= 1) mx = fmaxf(mx, __shfl_down(mx, o));
  __shared__ float red[4];
  __shared__ float bm, bz;
  if ((t & 63) == 0) red[t >> 6] = mx;
  __syncthreads();
  if (t == 0) bm = fmaxf(fmaxf(red[0], red[1]), fmaxf(red[2], red[3]));
  __syncthreads();
  const float M = bm;
  const float e0 = expf(v.x - M), e1 = expf(v.y - M);
  float s = e0 + e1;
#pragma unroll
  for (int o = 32; o > 0; o >>= 1) s += __shfl_down(s, o);
  if ((t & 63) == 0) red[t >> 6] = s;
  __syncthreads();
  if (t == 0) bz = 1.f / (red[0] + red[1] + red[2] + red[3]);
  __syncthreads();
  ushort2 u; u.x = f2bf(e0 * bz); u.y = f2bf(e1 * bz);
  *(ushort2*)(out + n * 512 + t * 2) = u;
}

__global__ __launch_bounds__(256) void gate_k(const float* __restrict__ xn,
                                              const float* __restrict__ gw,
                                              const float* __restrict__ gb,
                                              float* __restrict__ gate) {
  const long n = blockIdx.x;
  const int t = threadIdx.x;
  const float4 v = ((const float4*)(xn + n * 1024))[t];
  const float4 g = ((const float4*)gw)[t];
  float s = v.x * g.x + v.y * g.y + v.z * g.z + v.w * g.w;
#pragma unroll
  for (int o = 32; o > 0; o >>= 1) s += __shfl_down(s, o);
  __shared__ float red[4];
  if ((t & 63) == 0) red[t >> 6] = s;
  __syncthreads();
  if (t == 0) {
    const float tot = red[0] + red[1] + red[2] + red[3] + gb[0];
    gate[n] = 1.f / (1.f + expf(-tot));
  }
}

extern "C" void kernel_launch(void* const* d_in, const int* in_sizes, int n_in,
                              void* d_out, int out_size, void* d_ws, size_t ws_size,
                              hipStream_t stream) {
  (void)in_sizes; (void)n_in; (void)out_size; (void)ws_size;
  const float* x    = (const float*)d_in[0];
  const float* prim = (const float*)d_in[1];
  const float* n1w  = (const float*)d_in[2];
  const float* qkvw = (const float*)d_in[3];
  const float* aow  = (const float*)d_in[4];
  const float* n2w  = (const float*)d_in[5];
  const float* rw   = (const float*)d_in[6];
  const float* w1   = (const float*)d_in[7];
  const float* w2   = (const float*)d_in[8];
  const float* n3w  = (const float*)d_in[9];
  const float* tqw  = (const float*)d_in[10];
  const float* tkw  = (const float*)d_in[11];
  const float* tvw  = (const float*)d_in[12];
  const float* tow  = (const float*)d_in[13];
  const float* tgw  = (const float*)d_in[14];
  const float* tgb  = (const float*)d_in[15];

  float* xbuf = (float*)d_out;
  float* aux  = xbuf + 4194304;

  char* W = (char*)d_ws;
  float* xn            = (float*)W;                           // 16 MB
  unsigned short* xnb  = (unsigned short*)(W + (16u << 20));  // 8 MB (hi)
  unsigned short* xnl  = (unsigned short*)(W + (24u << 20));  // 8 MB (lo)
  char* P = W + (32u << 20);

  // phase A
  unsigned short* qh   = (unsigned short*)(P + (48u << 20));
  unsigned short* ql   = (unsigned short*)(P + (56u << 20));
  unsigned short* kh   = (unsigned short*)(P + (64u << 20));
  unsigned short* kl   = (unsigned short*)(P + (72u << 20));
  unsigned short* vh   = (unsigned short*)(P + (80u << 20));
  unsigned short* vl   = (unsigned short*)(P + (88u << 20));
  unsigned short* vth  = (unsigned short*)(P + (96u << 20));   // V^T hi (8 MB)
  unsigned short* vtl  = (unsigned short*)(P + (104u << 20));  // V^T lo (8 MB)
  unsigned short* axh  = (unsigned short*)(P + (112u << 20));
  unsigned short* axl  = (unsigned short*)(P + (120u << 20));
  unsigned short* qwh  = (unsigned short*)(P + (128u << 20));
  unsigned short* qwl  = (unsigned short*)(P + (134u << 20));
  unsigned short* aoh  = (unsigned short*)(P + (140u << 20));
  unsigned short* aol  = (unsigned short*)(P + (142u << 20));
  // phase B (aliases phase A)
  int*   topi = (int*)P;
  float* topw = (float*)(P + 65536);
  int*   slot = (int*)(P + 131072);
  int*   keep = (int*)(P + 196608);
  float* cnt  = (float*)(P + 262144);
  float* psum = (float*)(P + 262144 + 4096);
  int*   s2t  = (int*)(P + 327680);
  float* s2w  = (float*)(P + 393216);
  float* probs = (float*)(P + 458752);                        // 256 KB
  unsigned short* bufb = (unsigned short*)(P + (1u << 20));   // 21 MB
  unsigned short* hb   = (unsigned short*)(P + (22u << 20));  // 42 MB
  unsigned short* Wt   = (unsigned short*)(P + (64u << 20));  // 67 MB
  // phase C (aliases again)
  unsigned short* tqb  = (unsigned short*)P;
  unsigned short* tkb  = (unsigned short*)(P + (2u << 20));
  unsigned short* tvtb = (unsigned short*)(P + (3u << 20));
  float*          tsc  = (float*)(P + (4u << 20));
  unsigned short* tpb  = (unsigned short*)(P + (12u << 20));
  unsigned short* tavb = (unsigned short*)(P + (16u << 20));
  float*          gate = (float*)(P + (18u << 20));
  unsigned short* tqwb = (unsigned short*)(P + (19u << 20));
  unsigned short* tkwb = (unsigned short*)(P + (20u << 20));
  unsigned short* tvwb = (unsigned short*)(P + (21u << 20));
  unsigned short* towb = (unsigned short*)(P + (22u << 20));
  unsigned short* primb= (unsigned short*)(P + (23u << 20));

  // ---- phase A: x += rope_attention(rmsnorm(x)) ----
  rmsnorm_k<0, 1><<<4096, 256, 0, stream>>>(x, n1w, nullptr, xnb, xnl);
  split2_k<<<4096, 256, 0, stream>>>(qkvw, qwh, qwl, aow, aoh, aol);
  bgemm_s<3><<<dim3(24, 32, 1), 256, 0, stream>>>(xnb, xnl, qwh, qwl, nullptr,
      4096, 3072, 1024, nullptr, qh, ql, kh, kl, vh, vl);
  cvt_tb_k<<<dim3(2, 64, 64), 256, 0, stream>>>(vh, vth, vl, vtl);
  flash_k<<<dim3(16, 32), 256, 0, stream>>>(qh, ql, kh, kl, vth, vtl, axh, axl);
  bgemm_s<2><<<dim3(8, 32, 1), 256, 0, stream>>>(axh, axl, aoh, aol, xbuf,
      4096, 1024, 1024, x, nullptr, nullptr, nullptr, nullptr, nullptr, nullptr);

  // ---- phase B: MoE ----
  rmsnorm_k<1, 0><<<4096, 256, 0, stream>>>(xbuf, n2w, xn, xnb, nullptr);
  router_k<<<4096, 256, 0, stream>>>(xn, rw, topi, topw, probs);
  psum_k<<<1, 256, 0, stream>>>(probs, psum);
  pos_k<<<1, 256, 0, stream>>>(topi, topw, slot, keep, s2t, s2w, cnt);
  scatter_b_k<<<8192, 128, 0, stream>>>(xnb, topi, slot, keep, bufb);
  cvt_t_k<<<dim3(64, 32, 16), 256, 0, stream>>>(w1, Wt, 1024, 2048);
  bgemm<3><<<dim3(16, 5, 16), 256, 0, stream>>>(bufb, Wt, hb, 640, 2048, 1024,
      (long)640 * 1024, (long)2048 * 1024, (long)640 * 2048, 1.f, nullptr, nullptr, nullptr);
  cvt_t_k<<<dim3(32, 64, 16), 256, 0, stream>>>(w2, Wt, 2048, 1024);
  bgemm<5><<<dim3(8, 5, 16), 256, 0, stream>>>(hb, Wt, xbuf, 640, 1024, 2048,
      (long)640 * 2048, (long)1024 * 2048, 0, 1.f, nullptr, s2t, s2w);
  aux_k<<<1, 64, 0, stream>>>(cnt, psum, aux);

  // ---- phase C: tou cross-attn ----
  rmsnorm_k<1, 0><<<4096, 256, 0, stream>>>(xbuf, n3w, xn, xnb, nullptr);
  cvt5_k<<<768, 256, 0, stream>>>(tqw, tqwb, tkw, tkwb, tvw, tvwb, tow, towb, prim, primb);
  bgemm<2><<<dim3(2, 32, 1), 256, 0, stream>>>(xnb, tqwb, tqb, 4096, 256, 1024, 0, 0, 0, 1.f, nullptr, nullptr, nullptr);
  bgemm<2><<<dim3(2, 4, 1), 256, 0, stream>>>(primb, tkwb, tkb, 512, 256, 256, 0, 0, 0, 1.f, nullptr, nullptr, nullptr);
  bgemm<2><<<dim3(4, 2, 1), 256, 0, stream>>>(tvwb, primb, tvtb, 256, 512, 256, 0, 0, 0, 1.f, nullptr, nullptr, nullptr);
  bgemm<0><<<dim3(4, 32, 1), 256, 0, stream>>>(tqb, tkb, tsc, 4096, 512, 256, 0, 0, 0, 0.0625f, nullptr, nullptr, nullptr);
  softmax512_k<<<4096, 256, 0, stream>>>(tsc, tpb);
  bgemm<2><<<dim3(2, 32, 1), 256, 0, stream>>>(tpb, tvtb, tavb, 4096, 256, 512, 0, 0, 0, 1.f, nullptr, nullptr, nullptr);
  gate_k<<<4096, 256, 0, stream>>>(xn, tgw, tgb, gate);
  bgemm<4><<<dim3(8, 32, 1), 256, 0, stream>>>(tavb, towb, xbuf, 4096, 1024, 256, 0, 0, 0, 1.f, gate, nullptr, nullptr);
}